// Round 1
// baseline (1781.124 us; speedup 1.0000x reference)
//
#include <hip/hip_runtime.h>
#include <hip/hip_bf16.h>
#include <math.h>

// UniPhyModel: B=2,T=8,C=4,H=W=128,P=8,D=128,DEPTH=2,E=4,HD=256,Hp=Wp=16,F2=256,CPP=256
// Tokens N = B*T*Hp*Wp = 4096, token n = ((b*T+t)*16+hp)*16+wp, latent layout [n][128] (re/im split)

#define NIN 28

__device__ __forceinline__ float d_sigmoid(float x){ return 1.0f/(1.0f+expf(-x)); }
__device__ __forceinline__ float d_softplus(float x){ return fmaxf(x,0.0f)+log1pf(expf(-fabsf(x))); }
__device__ __forceinline__ float d_gelu(float x){
  const float c=0.7978845608028654f;
  return 0.5f*x*(1.0f+tanhf(c*(x+0.044715f*x*x*x)));
}

// ---------- dtype detect + convert all inputs to f32 arena ----------
__global__ void detect_k(const void* lnspg, int* flag){
  unsigned w=*(const unsigned*)lnspg;        // ln_sp_g is all-ones
  *flag=(w==0x3F803F80u)?1:0;                // bf16 pair of 1.0 vs f32 1.0
}

struct CvtArgs { const void* src[NIN]; int cum[NIN+1]; };

__global__ __launch_bounds__(256) void convert_k(CvtArgs a, const int* flag, float* dst, int total){
  int g=blockIdx.x*256+threadIdx.x;
  if(g>=total) return;
  int i=0;
  while(i<NIN-1 && g>=a.cum[i+1]) i++;
  int local=g-a.cum[i];
  float v;
  if(*flag) v=__bfloat162float(((const __hip_bfloat16*)a.src[i])[local]);
  else      v=((const float*)a.src[i])[local];
  dst[g]=v;
}

// ---------- patch gather: f[n][cpp] = x[b,t,c,hp*8+ph,wp*8+pw], cpp=c*64+ph*8+pw ----------
__global__ __launch_bounds__(256) void gather_k(const float* __restrict__ x, float* __restrict__ f){
  int i=blockIdx.x*256+threadIdx.x;          // < 4096*256
  int cpp=i&255, n=i>>8;
  int wp=n&15, hp=(n>>4)&15, bt=n>>8;
  int c=cpp>>6, ph=(cpp>>3)&7, pw=cpp&7;
  size_t src=(((size_t)bt*4+c)<<14)+(size_t)((hp*8+ph)<<7)+(wp*8+pw);
  f[i]=x[src];
}

// ---------- generic f32 GEMM: C[M,N] = act(A[M,K] @ W[K,N] + bias); A optionally split (A1|A2) ----------
__global__ __launch_bounds__(256) void gemm_k(
    const float* __restrict__ A1, const float* __restrict__ A2,
    const float* __restrict__ W, const float* __restrict__ bias,
    float* __restrict__ C, const float* __restrict__ rowscale,
    int M, int N, int K, int act, int rsStride, int accum){
  __shared__ float As[16][65];
  __shared__ float Ws[16][65];
  const int bm=blockIdx.y*64, bn=blockIdx.x*64;
  const int tid=threadIdx.x, tr=tid>>4, tc=tid&15;
  const int halfK=K>>1;
  float acc[4][4]={};
  for(int k0=0;k0<K;k0+=16){
    #pragma unroll
    for(int l=0;l<4;l++){
      int e=tid+l*256;                        // 0..1023
      int r=e>>4, kk=e&15;
      int gk=k0+kk;
      float av;
      if(A2) av=(gk<halfK)? A1[(size_t)(bm+r)*halfK+gk] : A2[(size_t)(bm+r)*halfK+gk-halfK];
      else   av=A1[(size_t)(bm+r)*K+gk];
      As[kk][r]=av;
      int kk2=e>>6, nn=e&63;
      Ws[kk2][nn]=W[(size_t)(k0+kk2)*N+bn+nn];
    }
    __syncthreads();
    #pragma unroll
    for(int kk=0;kk<16;kk++){
      float a[4],w[4];
      #pragma unroll
      for(int ii=0;ii<4;ii++) a[ii]=As[kk][(tr<<2)+ii];
      #pragma unroll
      for(int jj=0;jj<4;jj++) w[jj]=Ws[kk][(tc<<2)+jj];
      #pragma unroll
      for(int ii=0;ii<4;ii++)
        #pragma unroll
        for(int jj=0;jj<4;jj++)
          acc[ii][jj]+=a[ii]*w[jj];
    }
    __syncthreads();
  }
  #pragma unroll
  for(int ii=0;ii<4;ii++){
    int m=bm+(tr<<2)+ii;
    float rs=rowscale? rowscale[(size_t)m*rsStride] : 1.0f;
    #pragma unroll
    for(int jj=0;jj<4;jj++){
      int n=bn+(tc<<2)+jj;
      float v=acc[ii][jj];
      if(bias) v+=bias[n];
      if(act==1) v=d_gelu(v);
      v*=rs;
      size_t o=(size_t)m*N+n;
      if(accum) C[o]+=v; else C[o]=v;
    }
  }
}

// ---------- complex GEMM: C = A @ (Wre + i Wim), A complex (Ar,Ai) ----------
__global__ __launch_bounds__(256) void cgemm_k(
    const float* __restrict__ Ar, const float* __restrict__ Ai,
    const float* __restrict__ Wre, const float* __restrict__ Wim,
    float* __restrict__ Cr, float* __restrict__ Ci, int M, int N, int K){
  __shared__ float Ars[16][65], Ais[16][65], Wrs[16][65], Wis[16][65];
  const int bm=blockIdx.y*64, bn=blockIdx.x*64;
  const int tid=threadIdx.x, tr=tid>>4, tc=tid&15;
  float ar4[4][4]={}, ai4[4][4]={};
  for(int k0=0;k0<K;k0+=16){
    #pragma unroll
    for(int l=0;l<4;l++){
      int e=tid+l*256;
      int r=e>>4, kk=e&15;
      int gk=k0+kk;
      Ars[kk][r]=Ar[(size_t)(bm+r)*K+gk];
      Ais[kk][r]=Ai[(size_t)(bm+r)*K+gk];
      int kk2=e>>6, nn=e&63;
      Wrs[kk2][nn]=Wre[(size_t)(k0+kk2)*N+bn+nn];
      Wis[kk2][nn]=Wim[(size_t)(k0+kk2)*N+bn+nn];
    }
    __syncthreads();
    #pragma unroll
    for(int kk=0;kk<16;kk++){
      float ar[4],ai[4],wr[4],wi[4];
      #pragma unroll
      for(int ii=0;ii<4;ii++){ ar[ii]=Ars[kk][(tr<<2)+ii]; ai[ii]=Ais[kk][(tr<<2)+ii]; }
      #pragma unroll
      for(int jj=0;jj<4;jj++){ wr[jj]=Wrs[kk][(tc<<2)+jj]; wi[jj]=Wis[kk][(tc<<2)+jj]; }
      #pragma unroll
      for(int ii=0;ii<4;ii++)
        #pragma unroll
        for(int jj=0;jj<4;jj++){
          ar4[ii][jj]+=ar[ii]*wr[jj]-ai[ii]*wi[jj];
          ai4[ii][jj]+=ar[ii]*wi[jj]+ai[ii]*wr[jj];
        }
    }
    __syncthreads();
  }
  #pragma unroll
  for(int ii=0;ii<4;ii++){
    int m=bm+(tr<<2)+ii;
    #pragma unroll
    for(int jj=0;jj<4;jj++){
      int n=bn+(tc<<2)+jj;
      Cr[(size_t)m*N+n]=ar4[ii][jj];
      Ci[(size_t)m*N+n]=ai4[ii][jj];
    }
  }
}

// ---------- LayerNorm over 256 = concat(re,im) per token ----------
__global__ __launch_bounds__(256) void ln_kernel(const float* __restrict__ Are, const float* __restrict__ Aim,
    const float* __restrict__ g, const float* __restrict__ b, float* __restrict__ out){
  int n=blockIdx.x; int tid=threadIdx.x;
  float v=(tid<128)? Are[(size_t)n*128+tid] : Aim[(size_t)n*128+tid-128];
  __shared__ float red[256];
  red[tid]=v; __syncthreads();
  for(int s=128;s>0;s>>=1){ if(tid<s) red[tid]+=red[tid+s]; __syncthreads(); }
  float mean=red[0]*(1.0f/256.0f);
  __syncthreads();
  float d=v-mean;
  red[tid]=d*d; __syncthreads();
  for(int s=128;s>0;s>>=1){ if(tid<s) red[tid]+=red[tid+s]; __syncthreads(); }
  float var=red[0]*(1.0f/256.0f);
  float rs=rsqrtf(var+1e-5f);
  out[(size_t)n*256+tid]=d*rs*g[tid]+b[tid];
}

// ---------- conv weight transpose: Wt[(ky*3+kx)*256+ic][o] = W[o][ic][ky][kx] ----------
__global__ __launch_bounds__(256) void convw_t_k(const float* __restrict__ Wsrc, float* __restrict__ Wt){
  int idx=blockIdx.x*256+threadIdx.x;        // < 2304*256
  int o=idx&255; int k=idx>>8;
  int ic=k&255; int kg=k>>8; int ky=kg/3, kx=kg-ky*3;
  Wt[(size_t)k*256+o]=Wsrc[((((size_t)o<<8)+ic)*3+ky)*3+kx];
}

// ---------- implicit-GEMM 3x3 conv + residual into zc ----------
__global__ __launch_bounds__(256) void conv_gemm(const float* __restrict__ xn, const float* __restrict__ Wt,
    const float* __restrict__ cb, float* __restrict__ zcr, float* __restrict__ zci){
  __shared__ float As[16][65];
  __shared__ float Ws[16][65];
  const int bm=blockIdx.y*64, bn=blockIdx.x*64;  // M=4096 tokens, N=256 out ch
  const int tid=threadIdx.x, tr=tid>>4, tc=tid&15;
  const int bt=bm>>8;            // image index (64-token tile stays in one image)
  const int y0=(bm>>4)&15;       // starting row (tiles cover rows y0..y0+3)
  float acc[4][4]={};
  for(int k0=0;k0<2304;k0+=16){
    #pragma unroll
    for(int l=0;l<4;l++){
      int e=tid+l*256;
      int r=e>>4, kk=e&15;
      int gk=k0+kk;
      int kg=gk>>8;              // ky*3+kx
      int ic=gk&255;
      int ky=kg/3, kx=kg-ky*3;
      int y=y0+(r>>4)+ky-1;
      int x=(r&15)+kx-1;
      float v=0.0f;
      if((unsigned)y<16u && (unsigned)x<16u)
        v=xn[((((size_t)bt<<4)+y)*16+x)*256+ic];
      As[kk][r]=v;
      int kk2=e>>6, nn=e&63;
      Ws[kk2][nn]=Wt[(size_t)(k0+kk2)*256+bn+nn];
    }
    __syncthreads();
    #pragma unroll
    for(int kk=0;kk<16;kk++){
      float a[4],w[4];
      #pragma unroll
      for(int ii=0;ii<4;ii++) a[ii]=As[kk][(tr<<2)+ii];
      #pragma unroll
      for(int jj=0;jj<4;jj++) w[jj]=Ws[kk][(tc<<2)+jj];
      #pragma unroll
      for(int ii=0;ii<4;ii++)
        #pragma unroll
        for(int jj=0;jj<4;jj++)
          acc[ii][jj]+=a[ii]*w[jj];
    }
    __syncthreads();
  }
  #pragma unroll
  for(int ii=0;ii<4;ii++){
    int m=bm+(tr<<2)+ii;
    #pragma unroll
    for(int jj=0;jj<4;jj++){
      int o=bn+(tc<<2)+jj;
      float v=acc[ii][jj]+cb[o];
      if(o<128) zcr[(size_t)m*128+o]+=v;
      else      zci[(size_t)m*128+o-128]+=v;
    }
  }
}

// ---------- xm = mean over 256 spatial of xe, per (b,t,d) ----------
__global__ __launch_bounds__(256) void reduce_xm_k(const float* __restrict__ xer, const float* __restrict__ xei,
    float* __restrict__ xmr, float* __restrict__ xmi){
  int bt=blockIdx.x; int tid=threadIdx.x;
  int d=tid&127; bool isIm=tid>=128;
  const float* src=isIm? xei:xer;
  float s=0.0f;
  for(int sp=0;sp<256;sp++) s+=src[(((size_t)bt<<8)+sp)*128+d];
  s*=(1.0f/256.0f);
  if(isIm) xmi[bt*128+d]=s; else xmr[bt*128+d]=s;
}

// ---------- ZOH operators: opd = exp(dt*lam), opf = (opd-1)/lam, lam = -softplus(lr)+i*li ----------
__global__ __launch_bounds__(256) void opd_opf_k(const float* __restrict__ dt,
    const float* __restrict__ lam_re, const float* __restrict__ lam_im,
    float* __restrict__ odr_, float* __restrict__ odi_, float* __restrict__ ofr_, float* __restrict__ ofi_){
  int idx=blockIdx.x*256+threadIdx.x;
  if(idx>=1024) return;
  int t=idx>>7, d=idx&127;
  float lr=-d_softplus(lam_re[d]);
  float li=lam_im[d];
  float dtv=dt[t];
  float er=expf(dtv*lr);
  float odr=er*cosf(dtv*li), odi=er*sinf(dtv*li);
  float den=lr*lr+li*li;
  float ar=odr-1.0f, ai=odi;
  odr_[idx]=odr; odi_[idx]=odi;
  ofr_[idx]=(ar*lr+ai*li)/den;
  ofi_[idx]=(ai*lr-ar*li)/den;
}

// ---------- recurrent flux tracker over T (2 blocks, one per batch) ----------
__global__ __launch_bounds__(256) void flux_scan(const float* __restrict__ xmr, const float* __restrict__ xmi,
    const float* __restrict__ gW, const float* __restrict__ gb,
    const float* __restrict__ sW, const float* __restrict__ sb,
    const float* __restrict__ fdec,
    float* __restrict__ fluxr, float* __restrict__ fluxi,
    float* __restrict__ fsr, float* __restrict__ fsi,
    float* __restrict__ ssr, float* __restrict__ ssi,
    float* __restrict__ gbuf, int initFlux){
  int b=blockIdx.x; int tid=threadIdx.x;
  __shared__ float inp[256], s2s[256], gts[128], flr[128], fli[128];
  if(tid<128){
    flr[tid]=initFlux?0.0f:fluxr[b*128+tid];
    fli[tid]=initFlux?0.0f:fluxi[b*128+tid];
  }
  __syncthreads();
  for(int t=0;t<8;t++){
    int base=(b*8+t)*128;
    inp[tid]=(tid<128)? xmr[base+tid] : xmi[base+tid-128];
    __syncthreads();
    float acc=sb[tid];
    for(int k=0;k<256;k++) acc+=inp[k]*sW[k*256+tid];
    s2s[tid]=acc;
    if(tid<128){
      float ag=gb[tid];
      for(int k=0;k<256;k++) ag+=inp[k]*gW[k*128+tid];
      gts[tid]=d_sigmoid(ag);
    }
    __syncthreads();
    if(tid<128){
      int d=tid;
      float xr=xmr[base+d], xi=xmi[base+d];
      float sr=s2s[d], si=s2s[128+d];
      float dec=d_sigmoid(fdec[d]);
      float gt=gts[d];
      float fnr=dec*flr[d]+gt*xr+(1.0f-gt)*sr;
      float fni=dec*fli[d]+gt*xi+(1.0f-gt)*si;
      flr[d]=fnr; fli[d]=fni;
      fsr[base+d]=fnr; fsi[base+d]=fni;
      ssr[base+d]=sr;  ssi[base+d]=si;
    }
    __syncthreads();
    inp[tid]=(tid<128)? flr[tid] : fli[tid-128];
    __syncthreads();
    if(tid<128){
      float ag=gb[tid];
      for(int k=0;k<256;k++) ag+=inp[k]*gW[k*128+tid];
      gbuf[base+tid]=d_sigmoid(ag);
    }
    __syncthreads();
  }
  if(tid<128){ fluxr[b*128+tid]=flr[tid]; fluxi[b*128+tid]=fli[tid]; }
}

// ---------- u = (xe*g + src*(1-g)) * opf, in place on xe ----------
__global__ __launch_bounds__(256) void forcing_u(float* __restrict__ xer, float* __restrict__ xei,
    const float* __restrict__ gbuf, const float* __restrict__ ssr, const float* __restrict__ ssi,
    const float* __restrict__ ofr, const float* __restrict__ ofi){
  int j=blockIdx.x*256+threadIdx.x;          // < 524288
  int d=j&127;
  int n=j>>7;
  int bt=n>>8;
  int t=bt&7;
  int bd=bt*128+d;
  int td=t*128+d;
  float g=gbuf[bd];
  float fr=xer[j]*g+ssr[bd]*(1.0f-g);
  float fi=xei[j]*g+ssi[bd]*(1.0f-g);
  float r=ofr[td], im=ofi[td];
  xer[j]=fr*r-fi*im;
  xei[j]=fr*im+fi*r;
}

// ---------- inclusive time scan h_t = A_t h_{t-1} + u_t, in place ----------
__global__ __launch_bounds__(256) void scan_t(float* __restrict__ ur, float* __restrict__ ui,
    const float* __restrict__ odr, const float* __restrict__ odi){
  int idx=blockIdx.x*256+threadIdx.x;        // < 65536: (b,s,d)
  int d=idx&127;
  int s=(idx>>7)&255;
  int b=idx>>15;
  float hr=0.0f, hi=0.0f;
  for(int t=0;t<8;t++){
    size_t j=((((size_t)(b*8+t)<<8)+s)<<7)+d;
    float ar=odr[t*128+d], ai=odi[t*128+d];
    float nr=ar*hr-ai*hi+ur[j];
    float ni=ar*hi+ai*hr+ui[j];
    hr=nr; hi=ni;
    ur[j]=hr; ui[j]=hi;
  }
}

// ---------- MoE router softmax ----------
__global__ __launch_bounds__(256) void gates_k(const float* __restrict__ ft, const float* __restrict__ rtr,
    float* __restrict__ gates){
  int m=blockIdx.x*256+threadIdx.x;          // < 4096
  const float* row=ft+(size_t)m*256;
  float a0=0,a1=0,a2=0,a3=0;
  for(int k=0;k<256;k++){
    float v=row[k];
    a0+=v*rtr[k*4+0]; a1+=v*rtr[k*4+1]; a2+=v*rtr[k*4+2]; a3+=v*rtr[k*4+3];
  }
  float mx=fmaxf(fmaxf(a0,a1),fmaxf(a2,a3));
  float e0=expf(a0-mx),e1=expf(a1-mx),e2=expf(a2-mx),e3=expf(a3-mx);
  float s=e0+e1+e2+e3;
  gates[m*4+0]=e0/s; gates[m*4+1]=e1/s; gates[m*4+2]=e2/s; gates[m*4+3]=e3/s;
}

// ---------- zc += xcc + delta  (ft = LN output = concat(xcc), dtok = MoE delta concat) ----------
__global__ __launch_bounds__(256) void residual_k(float* __restrict__ zcr, float* __restrict__ zci,
    const float* __restrict__ ft, const float* __restrict__ dtok){
  int j=blockIdx.x*256+threadIdx.x;          // < 524288
  int n=j>>7, d=j&127;
  size_t o=(size_t)n*256;
  zcr[j]+=ft[o+d]+dtok[o+d];
  zci[j]+=ft[o+128+d]+dtok[o+128+d];
}

// ---------- unpatchify + output store (dtype per flag) ----------
__global__ __launch_bounds__(256) void unpatch_k(const float* __restrict__ fo, void* dout, const int* flag){
  int o=blockIdx.x*256+threadIdx.x;          // < 1048576
  int w=o&127;
  int y=(o>>7)&127;
  int c=(o>>14)&3;
  int bt=o>>16;
  int hp=y>>3, ph=y&7, wp=w>>3, pw=w&7;
  int n=(bt<<8)+(hp<<4)+wp;
  int cpp=(c<<6)+(ph<<3)+pw;
  float v=fo[(size_t)n*256+cpp];
  if(*flag) ((__hip_bfloat16*)dout)[o]=__float2bfloat16(v);
  else      ((float*)dout)[o]=v;
}

extern "C" void kernel_launch(void* const* d_in, const int* in_sizes, int n_in,
                              void* d_out, int out_size, void* d_ws, size_t ws_size,
                              hipStream_t stream){
  (void)out_size; (void)ws_size; (void)n_in;
  // ---- arena layout ----
  int cum[NIN+1]; cum[0]=0;
  for(int i=0;i<NIN;i++) cum[i+1]=cum[i]+in_sizes[i];
  const int total=cum[NIN];
  float* arena=(float*)d_ws;
  size_t off=((size_t)total+255)&~(size_t)255;
  int* flag=(int*)(arena+off); off+=256;
  float* big0 =arena+off; off+=1048576;      // f / dtok / fo (time-disjoint)
  float* zc_re=arena+off; off+=524288;
  float* zc_im=arena+off; off+=524288;
  float* xn   =arena+off; off+=1048576;      // LN-out for conv; reused as hmid in MoE
  float* xe_re=arena+off; off+=524288;       // xe -> u -> uo (in place)
  float* xe_im=arena+off; off+=524288;
  float* xo_re=arena+off; off+=524288;
  float* xo_im=arena+off; off+=524288;
  float* ft   =arena+off; off+=1048576;
  float* Wt   =arena+off; off+=589824;
  float* xm_re=arena+off; off+=2048;
  float* xm_im=arena+off; off+=2048;
  float* fsr  =arena+off; off+=2048;
  float* fsi  =arena+off; off+=2048;
  float* ssr  =arena+off; off+=2048;
  float* ssi  =arena+off; off+=2048;
  float* gbuf =arena+off; off+=2048;
  float* odr  =arena+off; off+=1024;
  float* odi  =arena+off; off+=1024;
  float* ofr  =arena+off; off+=1024;
  float* ofi  =arena+off; off+=1024;
  float* gates=arena+off; off+=16384;
  float* fluxr=arena+off; off+=256;
  float* fluxi=arena+off; off+=256;

  // ---- dtype detect + convert ----
  detect_k<<<1,1,0,stream>>>(d_in[6], flag);
  CvtArgs ca;
  for(int i=0;i<NIN;i++) ca.src[i]=d_in[i];
  for(int i=0;i<=NIN;i++) ca.cum[i]=cum[i];
  convert_k<<<(total+255)/256,256,0,stream>>>(ca, flag, arena, total);

  const float* A_x   =arena+cum[0];
  const float* A_dt  =arena+cum[1];
  const float* A_eWre=arena+cum[2];
  const float* A_eWim=arena+cum[3];
  const float* A_decW=arena+cum[4];
  const float* A_decb=arena+cum[5];

  // ---- encoder ----
  gather_k<<<4096,256,0,stream>>>(A_x, big0);
  gemm_k<<<dim3(2,64),256,0,stream>>>(big0,nullptr,A_eWre,nullptr,zc_re,nullptr,4096,128,256,0,0,0);
  gemm_k<<<dim3(2,64),256,0,stream>>>(big0,nullptr,A_eWim,nullptr,zc_im,nullptr,4096,128,256,0,0,0);

  for(int i=0;i<2;i++){
    const float* lnspg=arena+cum[6]+i*256;
    const float* lnspb=arena+cum[7]+i*256;
    const float* convW=arena+cum[8]+(size_t)i*589824;
    const float* convb=arena+cum[9]+i*256;
    const float* Ere  =arena+cum[10]+i*16384;
    const float* Eim  =arena+cum[11]+i*16384;
    const float* Dre  =arena+cum[12]+i*16384;
    const float* Dim  =arena+cum[13]+i*16384;
    const float* gW   =arena+cum[14]+i*32768;
    const float* gb   =arena+cum[15]+i*128;
    const float* sW   =arena+cum[16]+i*65536;
    const float* sb   =arena+cum[17]+i*256;
    const float* fdec =arena+cum[18]+i*128;
    const float* lamre=arena+cum[19]+i*128;
    const float* lamim=arena+cum[20]+i*128;
    const float* lntg =arena+cum[21]+i*256;
    const float* lntb =arena+cum[22]+i*256;
    const float* rtr  =arena+cum[23]+i*1024;

    // spatial branch
    ln_kernel<<<4096,256,0,stream>>>(zc_re,zc_im,lnspg,lnspb,xn);
    convw_t_k<<<2304,256,0,stream>>>(convW,Wt);
    conv_gemm<<<dim3(4,64),256,0,stream>>>(xn,Wt,convb,zc_re,zc_im);
    // eigen encode + spatial mean
    cgemm_k<<<dim3(2,64),256,0,stream>>>(zc_re,zc_im,Ere,Eim,xe_re,xe_im,4096,128,128);
    reduce_xm_k<<<16,256,0,stream>>>(xe_re,xe_im,xm_re,xm_im);
    // transition operators + flux recurrence
    opd_opf_k<<<4,256,0,stream>>>(A_dt,lamre,lamim,odr,odi,ofr,ofi);
    flux_scan<<<2,256,0,stream>>>(xm_re,xm_im,gW,gb,sW,sb,fdec,fluxr,fluxi,fsr,fsi,ssr,ssi,gbuf,(i==0)?1:0);
    forcing_u<<<2048,256,0,stream>>>(xe_re,xe_im,gbuf,ssr,ssi,ofr,ofi);
    scan_t<<<256,256,0,stream>>>(xe_re,xe_im,odr,odi);
    // basis decode + LN
    cgemm_k<<<dim3(2,64),256,0,stream>>>(xe_re,xe_im,Dre,Dim,xo_re,xo_im,4096,128,128);
    ln_kernel<<<4096,256,0,stream>>>(xo_re,xo_im,lntg,lntb,ft);
    // MoE
    gates_k<<<16,256,0,stream>>>(ft,rtr,gates);
    for(int e=0;e<4;e++){
      const float* W1=arena+cum[24]+((size_t)i*4+e)*65536;
      const float* b1=arena+cum[25]+((size_t)i*4+e)*256;
      const float* W2=arena+cum[26]+((size_t)i*4+e)*65536;
      const float* b2=arena+cum[27]+((size_t)i*4+e)*256;
      gemm_k<<<dim3(4,64),256,0,stream>>>(ft,nullptr,W1,b1,xn,nullptr,4096,256,256,1,0,0);
      gemm_k<<<dim3(4,64),256,0,stream>>>(xn,nullptr,W2,b2,big0,gates+e,4096,256,256,0,4,(e>0)?1:0);
    }
    residual_k<<<2048,256,0,stream>>>(zc_re,zc_im,ft,big0);
  }

  // ---- decoder ----
  gemm_k<<<dim3(4,64),256,0,stream>>>(zc_re,zc_im,A_decW,A_decb,big0,nullptr,4096,256,256,0,0,0);
  unpatch_k<<<4096,256,0,stream>>>(big0,d_out,flag);
}

// Round 2
// 467.993 us; speedup vs baseline: 3.8059x; 3.8059x over previous
//
#include <hip/hip_runtime.h>
#include <hip/hip_bf16.h>
#include <math.h>

// UniPhyModel: B=2,T=8,C=4,H=W=128,P=8,D=128,DEPTH=2,E=4,HD=256,Hp=Wp=16,F2=256,CPP=256
// Canonical activation layout: [n][256] where n=((b*T+t)*16+hp)*16+wp, cols = [re(128)|im(128)]
// All GEMMs: M=4096, N=256, K in {256, 2304}; weights pre-transposed to [N][K] bf16.

#define NIN 28
typedef unsigned short u16;
typedef __attribute__((ext_vector_type(8))) short bf16x8;
typedef __attribute__((ext_vector_type(4))) float f32x4;
typedef __attribute__((ext_vector_type(8))) unsigned short us8;

__device__ __forceinline__ float b2f(u16 u){ union{unsigned i;float f;}v; v.i=((unsigned)u)<<16; return v.f; }
__device__ __forceinline__ u16 f2b(float x){ __hip_bfloat16 h=__float2bfloat16(x); return *(u16*)&h; }
__device__ __forceinline__ float loadraw(const void* p, size_t i, int bf){
  return bf? b2f(((const u16*)p)[i]) : ((const float*)p)[i];
}
__device__ __forceinline__ float d_sigmoid(float x){ return 1.0f/(1.0f+expf(-x)); }
__device__ __forceinline__ float d_softplus(float x){ return fmaxf(x,0.0f)+log1pf(expf(-fabsf(x))); }
__device__ __forceinline__ float d_gelu(float x){
  const float c=0.7978845608028654f;
  return 0.5f*x*(1.0f+tanhf(c*(x+0.044715f*x*x*x)));
}

// ---------- dtype detect + convert small f32 params into arena ----------
__global__ void detect_k(const void* lnspg, int* flag){
  unsigned w=*(const unsigned*)lnspg;        // ln_sp_g is all-ones
  *flag=(w==0x3F803F80u)?1:0;                // bf16 pair of 1.0 vs f32 1.0
}

struct CvtArgs { const void* src[NIN]; int cum[NIN+1]; };

__global__ __launch_bounds__(256) void convert_k(CvtArgs a, const int* flag, float* dst, int total){
  int g=blockIdx.x*256+threadIdx.x;
  if(g>=total) return;
  int i=0;
  while(i<NIN-1 && g>=a.cum[i+1]) i++;
  int local=g-a.cum[i];
  dst[g]=loadraw(a.src[i], local, *flag);
}

// ---------- weight prep ----------
// encB[n][k]: n<128 -> Wre[k][n], else Wim[k][n-128]
__global__ __launch_bounds__(256) void prep_enc(const void* wre, const void* wim, u16* dst, const int* flag){
  int idx=blockIdx.x*256+threadIdx.x;        // 65536
  int n=idx>>8, k=idx&255;
  int bf=*flag;
  float v=(n<128)? loadraw(wre,(size_t)k*128+n,bf) : loadraw(wim,(size_t)k*128+(n-128),bf);
  dst[idx]=f2b(v);
}

// convB[i][o][k], k=(ky*3+kx)*256+ic, src convW[i][o][ic][ky][kx]
__global__ __launch_bounds__(256) void prep_conv(const void* w, u16* dst, const int* flag){
  int idx=blockIdx.x*256+threadIdx.x;        // 2*256*2304 = 1179648
  if(idx>=1179648) return;
  int i=idx/589824; int r=idx-i*589824;
  int o=r/2304; int k=r-o*2304;
  int kg=k>>8, ic=k&255; int ky=kg/3, kx=kg-3*ky;
  size_t src=((((size_t)i*256+o)*256+ic)*3+ky)*3+kx;
  dst[idx]=f2b(loadraw(w,src,*flag));
}

// cplxB[mat][n][k] for mats {E d0, E d1, Dc d0, Dc d1}: real-ified complex right-mult
// k<128: n<128 -> Wre[k][n] ; n>=128 -> Wim[k][n-128]
// k>=128: n<128 -> -Wim[k-128][n] ; n>=128 -> Wre[k-128][n-128]
__global__ __launch_bounds__(256) void prep_cplx(const void* ere, const void* eim,
    const void* dre, const void* dim, u16* dst, const int* flag){
  int idx=blockIdx.x*256+threadIdx.x;        // 4*65536
  int mat=idx>>16; int r=idx&65535; int n=r>>8, k=r&255;
  int depth=mat&1; int isD=mat>>1;
  const void* re=isD? dre:ere; const void* im=isD? dim:eim;
  size_t base=(size_t)depth*16384;
  int bf=*flag;
  float v;
  if(k<128){
    if(n<128) v= loadraw(re, base+(size_t)k*128+n, bf);
    else      v= loadraw(im, base+(size_t)k*128+(n-128), bf);
  }else{
    int kk=k-128;
    if(n<128) v=-loadraw(im, base+(size_t)kk*128+n, bf);
    else      v= loadraw(re, base+(size_t)kk*128+(n-128), bf);
  }
  dst[idx]=f2b(v);
}

// dst[m][n][k] = src[m][k][n], 256x256 mats
__global__ __launch_bounds__(256) void transpose256(const void* src, u16* dst, int nmat, const int* flag){
  int idx=blockIdx.x*256+threadIdx.x;
  if(idx>=nmat*65536) return;
  int m=idx>>16; int r=idx&65535; int n=r>>8, k=r&255;
  dst[idx]=f2b(loadraw(src,(size_t)m*65536+(size_t)k*256+n,*flag));
}

// ---------- patch gather -> bf16 f[n][cpp] ----------
__global__ __launch_bounds__(256) void gather_k(const void* x, u16* f, const int* flag){
  int i=blockIdx.x*256+threadIdx.x;          // 1048576
  int cpp=i&255, n=i>>8;
  int wp=n&15, hp=(n>>4)&15, bt=n>>8;
  int c=cpp>>6, ph=(cpp>>3)&7, pw=cpp&7;
  size_t src=(((size_t)bt*4+c)<<14)+(size_t)((hp*8+ph)<<7)+(wp*8+pw);
  f[i]= (*flag)? ((const u16*)x)[src] : f2b(((const float*)x)[src]);
}

// ---------- unified MFMA GEMM ----------
#define FB_BIAS 1
#define FB_GELU 2
#define FB_RS 4
#define FB_ATOMIC 8
#define FB_ADDTO 16
#define FB_WF32 32
#define FB_WBF16 64
#define FB_CONV 128

__global__ __launch_bounds__(256) void mfma_gemm(
    const u16* __restrict__ A, const u16* __restrict__ Bt,
    const float* __restrict__ bias, const float* __restrict__ rowscale,
    float* __restrict__ Cf, u16* __restrict__ Cb, float* __restrict__ Cat,
    int M, int N, int K, int flags,
    long aStride, long bStride, long biasStride, long cStride)
{
  __shared__ u16 As[64][72];                  // 144B row stride: 16B-aligned, 4-bank rotate/row
  __shared__ u16 Bs[64][72];
  const int e = blockIdx.z;
  A  += (size_t)e*aStride;
  Bt += (size_t)e*bStride;
  if(bias) bias += (size_t)e*biasStride;
  const int bn = blockIdx.x*64, bm = blockIdx.y*64;
  const int tid = threadIdx.x, l = tid&63, w = tid>>6;
  const int wm = w>>1, wn = w&1;
  const us8 z8 = {0,0,0,0,0,0,0,0};
  us8 ra[2], rb[2];

  auto loadA=[&](int k0, int i){
    int c = tid + (i<<8); int row=c>>3, col8=(c&7)<<3;
    if (flags & FB_CONV){
      int m = bm + row; int bt=m>>8, rem=m&255, hp=rem>>4, wp=rem&15;
      int gk=k0+col8; int kg=gk>>8, ic=gk&255; int ky=kg/3, kx=kg-3*ky;
      int y=hp+ky-1, x=wp+kx-1;
      if ((unsigned)y<16u && (unsigned)x<16u)
        ra[i] = *(const us8*)&A[(((size_t)(bt*16+y))*16+x)*256+ic];
      else ra[i] = z8;
    } else {
      ra[i] = *(const us8*)&A[(size_t)(bm+row)*K + k0 + col8];
    }
  };
  auto loadB=[&](int k0, int i){
    int c = tid + (i<<8); int row=c>>3, col8=(c&7)<<3;
    rb[i] = *(const us8*)&Bt[(size_t)(bn+row)*K + k0 + col8];
  };

  loadA(0,0); loadA(0,1); loadB(0,0); loadB(0,1);

  f32x4 zf = {0.f,0.f,0.f,0.f};
  f32x4 acc[2][2];
  acc[0][0]=zf; acc[0][1]=zf; acc[1][0]=zf; acc[1][1]=zf;

  const int kSteps = K>>6;
  for(int ks=0; ks<kSteps; ++ks){
    __syncthreads();                          // prior reads done
    {
      int c0=tid, c1=tid+256;
      *(us8*)&As[c0>>3][(c0&7)<<3] = ra[0];
      *(us8*)&As[c1>>3][(c1&7)<<3] = ra[1];
      *(us8*)&Bs[c0>>3][(c0&7)<<3] = rb[0];
      *(us8*)&Bs[c1>>3][(c1&7)<<3] = rb[1];
    }
    if(ks+1<kSteps){ int k0=(ks+1)<<6; loadA(k0,0); loadA(k0,1); loadB(k0,0); loadB(k0,1); }
    __syncthreads();                          // tile ready; next-tile loads in flight
    #pragma unroll
    for(int kk=0; kk<64; kk+=32){
      const int kc = kk + ((l>>4)<<3);
      bf16x8 a0 = *(const bf16x8*)&As[wm*32      + (l&15)][kc];
      bf16x8 a1 = *(const bf16x8*)&As[wm*32 + 16 + (l&15)][kc];
      bf16x8 b0 = *(const bf16x8*)&Bs[wn*32      + (l&15)][kc];
      bf16x8 b1 = *(const bf16x8*)&Bs[wn*32 + 16 + (l&15)][kc];
      acc[0][0] = __builtin_amdgcn_mfma_f32_16x16x32_bf16(a0,b0,acc[0][0],0,0,0);
      acc[0][1] = __builtin_amdgcn_mfma_f32_16x16x32_bf16(a0,b1,acc[0][1],0,0,0);
      acc[1][0] = __builtin_amdgcn_mfma_f32_16x16x32_bf16(a1,b0,acc[1][0],0,0,0);
      acc[1][1] = __builtin_amdgcn_mfma_f32_16x16x32_bf16(a1,b1,acc[1][1],0,0,0);
    }
  }

  const int rr = (l>>4)<<2;                   // C/D: col=lane&15, row=(lane>>4)*4+reg (m89/m91)
  const int cc = l&15;
  #pragma unroll
  for(int mi=0;mi<2;mi++)
  #pragma unroll
  for(int ni=0;ni<2;ni++)
  #pragma unroll
  for(int r=0;r<4;r++){
    int m = bm + wm*32 + mi*16 + rr + r;
    int n = bn + wn*32 + ni*16 + cc;
    float v = acc[mi][ni][r];
    if(flags&FB_BIAS) v += bias[n];
    if(flags&FB_GELU) v = d_gelu(v);
    if(flags&FB_RS)   v *= rowscale[(size_t)m*4 + e];
    size_t o = (size_t)e*cStride + (size_t)m*N + n;
    if(flags&FB_ATOMIC){ atomicAdd(&Cat[(size_t)m*N+n], v); continue; }
    if(flags&FB_ADDTO){ v += Cf[o]; }
    if(flags&(FB_WF32|FB_ADDTO)) Cf[o]=v;
    if(flags&FB_WBF16) Cb[o]=f2b(v);
  }
}

// ---------- LayerNorm over 256 cols, f32 in -> bf16 out ----------
__global__ __launch_bounds__(256) void ln_k(const float* __restrict__ X,
    const float* __restrict__ g, const float* __restrict__ b, u16* __restrict__ out){
  int n=blockIdx.x, tid=threadIdx.x;
  float v=X[(size_t)n*256+tid];
  __shared__ float red[256];
  red[tid]=v; __syncthreads();
  for(int s=128;s>0;s>>=1){ if(tid<s) red[tid]+=red[tid+s]; __syncthreads(); }
  float mean=red[0]*(1.0f/256.0f);
  __syncthreads();
  float d=v-mean;
  red[tid]=d*d; __syncthreads();
  for(int s=128;s>0;s>>=1){ if(tid<s) red[tid]+=red[tid+s]; __syncthreads(); }
  float rs=rsqrtf(red[0]*(1.0f/256.0f)+1e-5f);
  out[(size_t)n*256+tid]=f2b(d*rs*g[tid]+b[tid]);
}

// ---------- xm[bt][c] = mean over 256 spatial of xe ----------
__global__ __launch_bounds__(256) void reduce_xm(const float* __restrict__ xe, float* __restrict__ xm){
  int bt=blockIdx.x, c=threadIdx.x;
  float s=0.f;
  for(int sp=0;sp<256;sp++) s+=xe[((size_t)bt*256+sp)*256+c];
  xm[bt*256+c]=s*(1.0f/256.0f);
}

// ---------- ZOH operators ----------
__global__ __launch_bounds__(256) void opd_opf_k(const float* __restrict__ dt,
    const float* __restrict__ lam_re, const float* __restrict__ lam_im,
    float* __restrict__ odr_, float* __restrict__ odi_, float* __restrict__ ofr_, float* __restrict__ ofi_){
  int idx=blockIdx.x*256+threadIdx.x;
  if(idx>=1024) return;
  int t=idx>>7, d=idx&127;
  float lr=-d_softplus(lam_re[d]);
  float li=lam_im[d];
  float dtv=dt[t];
  float er=expf(dtv*lr);
  float odr=er*cosf(dtv*li), odi=er*sinf(dtv*li);
  float den=lr*lr+li*li;
  float ar=odr-1.0f, ai=odi;
  odr_[idx]=odr; odi_[idx]=odi;
  ofr_[idx]=(ar*lr+ai*li)/den;
  ofi_[idx]=(ai*lr-ar*li)/den;
}

// ---------- recurrent flux tracker (2 blocks) ----------
__global__ __launch_bounds__(256) void flux_scan(const float* __restrict__ xm,
    const float* __restrict__ gW, const float* __restrict__ gb,
    const float* __restrict__ sW, const float* __restrict__ sb,
    const float* __restrict__ fdec,
    float* __restrict__ fluxbuf,                       // [2][2][128] re/im
    float* __restrict__ ss, float* __restrict__ gbuf, int initFlux){
  int b=blockIdx.x; int tid=threadIdx.x;
  __shared__ float inp[256], s2s[256], gts[128], flr[128], fli[128];
  if(tid<128){
    flr[tid]=initFlux?0.0f:fluxbuf[b*256+tid];
    fli[tid]=initFlux?0.0f:fluxbuf[b*256+128+tid];
  }
  __syncthreads();
  for(int t=0;t<8;t++){
    int base=(b*8+t)*256;
    inp[tid]=xm[base+tid];
    __syncthreads();
    float acc=sb[tid];
    for(int k=0;k<256;k++) acc+=inp[k]*sW[k*256+tid];
    s2s[tid]=acc;
    if(tid<128){
      float ag=gb[tid];
      for(int k=0;k<256;k++) ag+=inp[k]*gW[k*128+tid];
      gts[tid]=d_sigmoid(ag);
    }
    __syncthreads();
    if(tid<128){
      int d=tid;
      float xr=xm[base+d], xi=xm[base+128+d];
      float sr=s2s[d], si=s2s[128+d];
      float dec=d_sigmoid(fdec[d]);
      float gt=gts[d];
      float fnr=dec*flr[d]+gt*xr+(1.0f-gt)*sr;
      float fni=dec*fli[d]+gt*xi+(1.0f-gt)*si;
      flr[d]=fnr; fli[d]=fni;
      ss[base+d]=sr; ss[base+128+d]=si;
    }
    __syncthreads();
    inp[tid]=(tid<128)? flr[tid] : fli[tid-128];
    __syncthreads();
    if(tid<128){
      float ag=gb[tid];
      for(int k=0;k<256;k++) ag+=inp[k]*gW[k*128+tid];
      gbuf[(b*8+t)*128+tid]=d_sigmoid(ag);
    }
    __syncthreads();
  }
  if(tid<128){ fluxbuf[b*256+tid]=flr[tid]; fluxbuf[b*256+128+tid]=fli[tid]; }
}

// ---------- fused forcing + inclusive time scan -> uo bf16 ----------
__global__ __launch_bounds__(256) void fscan_t(const float* __restrict__ xe,
    const float* __restrict__ gbuf, const float* __restrict__ ss,
    const float* __restrict__ odr, const float* __restrict__ odi,
    const float* __restrict__ ofr, const float* __restrict__ ofi, u16* __restrict__ uo){
  int idx=blockIdx.x*256+threadIdx.x;        // 65536 = (b,s,d)
  int d=idx&127, s=(idx>>7)&255, b=idx>>15;
  float hr=0.f, hi=0.f;
  for(int t=0;t<8;t++){
    int bt=b*8+t;
    size_t n=(size_t)bt*256+s;
    float g=gbuf[bt*128+d];
    float sr=ss[bt*256+d], si=ss[bt*256+128+d];
    float xr=xe[n*256+d], xi=xe[n*256+128+d];
    float fr=xr*g+sr*(1.0f-g), fi=xi*g+si*(1.0f-g);
    float pr=ofr[t*128+d], pi=ofi[t*128+d];
    float ur=fr*pr-fi*pi, ui=fr*pi+fi*pr;
    float ar=odr[t*128+d], ai=odi[t*128+d];
    float nr=ar*hr-ai*hi+ur, ni=ar*hi+ai*hr+ui;
    hr=nr; hi=ni;
    uo[n*256+d]=f2b(hr); uo[n*256+128+d]=f2b(hi);
  }
}

// ---------- router softmax ----------
__global__ __launch_bounds__(256) void gates_k(const u16* __restrict__ ft,
    const float* __restrict__ rtr, float* __restrict__ gates){
  int m=blockIdx.x*256+threadIdx.x;          // 4096
  float a0=0,a1=0,a2=0,a3=0;
  for(int k=0;k<256;k++){
    float v=b2f(ft[(size_t)m*256+k]);
    a0+=v*rtr[k*4+0]; a1+=v*rtr[k*4+1]; a2+=v*rtr[k*4+2]; a3+=v*rtr[k*4+3];
  }
  float mx=fmaxf(fmaxf(a0,a1),fmaxf(a2,a3));
  float e0=expf(a0-mx),e1=expf(a1-mx),e2=expf(a2-mx),e3=expf(a3-mx);
  float s=1.0f/(e0+e1+e2+e3);
  gates[m*4+0]=e0*s; gates[m*4+1]=e1*s; gates[m*4+2]=e2*s; gates[m*4+3]=e3*s;
}

// ---------- zc += ft + dtok ; refresh zc bf16 ----------
__global__ __launch_bounds__(256) void residual_k(float* __restrict__ zc, u16* __restrict__ zcb,
    const u16* __restrict__ ft, const float* __restrict__ dtok){
  size_t i=(size_t)blockIdx.x*256+threadIdx.x;  // 1048576
  float v=zc[i]+b2f(ft[i])+dtok[i];
  zc[i]=v; zcb[i]=f2b(v);
}

// ---------- unpatchify + output ----------
__global__ __launch_bounds__(256) void unpatch_k(const float* __restrict__ fo, void* dout, const int* flag){
  int o=blockIdx.x*256+threadIdx.x;          // 1048576
  int w=o&127;
  int y=(o>>7)&127;
  int c=(o>>14)&3;
  int bt=o>>16;
  int hp=y>>3, ph=y&7, wp=w>>3, pw=w&7;
  int n=(bt<<8)+(hp<<4)+wp;
  int cpp=(c<<6)+(ph<<3)+pw;
  float v=fo[(size_t)n*256+cpp];
  if(*flag) ((__hip_bfloat16*)dout)[o]=__float2bfloat16(v);
  else      ((float*)dout)[o]=v;
}

extern "C" void kernel_launch(void* const* d_in, const int* in_sizes, int n_in,
                              void* d_out, int out_size, void* d_ws, size_t ws_size,
                              hipStream_t stream){
  (void)out_size; (void)ws_size; (void)n_in;
  // arena holds f32 copies of everything EXCEPT x (index 0, biggest input)
  int acum[NIN+1]; acum[0]=0;
  for(int i=0;i<NIN;i++) acum[i+1]=acum[i]+((i==0)?0:in_sizes[i]);
  const int totalA=acum[NIN];
  float* W=(float*)d_ws;
  size_t off=((size_t)totalA+63)&~(size_t)63;
  int*   flag =(int*)(W+off); off+=64;
  float* zc   =W+off; off+=1048576;
  float* xe   =W+off; off+=1048576;          // also xo, fo (time-disjoint)
  float* dtok =W+off; off+=1048576;
  u16*  zcb  =(u16*)(W+off); off+=524288;
  u16*  xnb  =(u16*)(W+off); off+=524288;
  u16*  uob  =(u16*)(W+off); off+=524288;    // also encoder input f_b
  u16*  ftb  =(u16*)(W+off); off+=524288;
  u16*  hmid =(u16*)(W+off); off+=2097152;   // [4][4096][256]
  u16*  encB =(u16*)(W+off); off+=32768;
  u16*  decB =(u16*)(W+off); off+=32768;
  u16*  convB=(u16*)(W+off); off+=589824;    // [2][256][2304]
  u16*  cplxB=(u16*)(W+off); off+=131072;    // [4][256][256]: E0,E1,D0,D1
  u16*  w1B  =(u16*)(W+off); off+=262144;    // [8][256][256]
  u16*  w2B  =(u16*)(W+off); off+=262144;
  float* xm   =W+off; off+=4096;
  float* ss   =W+off; off+=4096;
  float* gbuf =W+off; off+=2048;
  float* odr  =W+off; off+=1024;
  float* odi  =W+off; off+=1024;
  float* ofr  =W+off; off+=1024;
  float* ofi  =W+off; off+=1024;
  float* gates=W+off; off+=16384;
  float* fluxb=W+off; off+=512;

  // ---- detect + convert + weight prep ----
  detect_k<<<1,1,0,stream>>>(d_in[6], flag);
  CvtArgs ca;
  for(int i=0;i<NIN;i++) ca.src[i]=d_in[i];
  for(int i=0;i<=NIN;i++) ca.cum[i]=acum[i];
  convert_k<<<(totalA+255)/256,256,0,stream>>>(ca, flag, W, totalA);
  prep_enc<<<256,256,0,stream>>>(d_in[2], d_in[3], encB, flag);
  transpose256<<<256,256,0,stream>>>(d_in[4], decB, 1, flag);
  prep_conv<<<4608,256,0,stream>>>(d_in[8], convB, flag);
  prep_cplx<<<1024,256,0,stream>>>(d_in[10], d_in[11], d_in[12], d_in[13], cplxB, flag);
  transpose256<<<2048,256,0,stream>>>(d_in[24], w1B, 8, flag);
  transpose256<<<2048,256,0,stream>>>(d_in[26], w2B, 8, flag);

  const dim3 GG(4,64,1);
  // ---- encoder: zc = f @ [Wre|Wim] ----
  gather_k<<<4096,256,0,stream>>>(d_in[0], uob, flag);
  mfma_gemm<<<GG,256,0,stream>>>(uob, encB, nullptr, nullptr, zc, zcb, nullptr,
                                 4096,256,256, FB_WF32|FB_WBF16, 0,0,0,0);

  for(int i=0;i<2;i++){
    const float* lnspg=W+acum[6]+i*256;
    const float* lnspb=W+acum[7]+i*256;
    const float* convb=W+acum[9]+i*256;
    const float* gW   =W+acum[14]+i*32768;
    const float* gb   =W+acum[15]+i*128;
    const float* sW   =W+acum[16]+i*65536;
    const float* sb   =W+acum[17]+i*256;
    const float* fdec =W+acum[18]+i*128;
    const float* lamre=W+acum[19]+i*128;
    const float* lamim=W+acum[20]+i*128;
    const float* lntg =W+acum[21]+i*256;
    const float* lntb =W+acum[22]+i*256;
    const float* rtr  =W+acum[23]+i*1024;
    const float* b1   =W+acum[25]+i*1024;
    const float* b2   =W+acum[27]+i*1024;

    // spatial branch: LN -> implicit-GEMM conv (+bias) accumulated into zc
    ln_k<<<4096,256,0,stream>>>(zc, lnspg, lnspb, xnb);
    mfma_gemm<<<GG,256,0,stream>>>(xnb, convB+(size_t)i*589824, convb, nullptr, zc, zcb, nullptr,
                                   4096,256,2304, FB_CONV|FB_BIAS|FB_ADDTO|FB_WBF16, 0,0,0,0);
    // eigen encode (complex as real 256x256)
    mfma_gemm<<<GG,256,0,stream>>>(zcb, cplxB+(size_t)i*65536, nullptr, nullptr, xe, nullptr, nullptr,
                                   4096,256,256, FB_WF32, 0,0,0,0);
    reduce_xm<<<16,256,0,stream>>>(xe, xm);
    opd_opf_k<<<4,256,0,stream>>>(W+acum[1], lamre, lamim, odr, odi, ofr, ofi);
    flux_scan<<<2,256,0,stream>>>(xm, gW, gb, sW, sb, fdec, fluxb, ss, gbuf, (i==0)?1:0);
    fscan_t<<<256,256,0,stream>>>(xe, gbuf, ss, odr, odi, ofr, ofi, uob);
    // basis decode + LN
    mfma_gemm<<<GG,256,0,stream>>>(uob, cplxB+(size_t)(2+i)*65536, nullptr, nullptr, xe, nullptr, nullptr,
                                   4096,256,256, FB_WF32, 0,0,0,0);
    ln_k<<<4096,256,0,stream>>>(xe, lntg, lntb, ftb);
    // MoE
    gates_k<<<16,256,0,stream>>>(ftb, rtr, gates);
    hipMemsetAsync(dtok, 0, 1048576*sizeof(float), stream);
    mfma_gemm<<<dim3(4,64,4),256,0,stream>>>(ftb, w1B+(size_t)i*262144, b1, nullptr, nullptr, hmid, nullptr,
                                   4096,256,256, FB_BIAS|FB_GELU|FB_WBF16, 0,65536,256,1048576);
    mfma_gemm<<<dim3(4,64,4),256,0,stream>>>(hmid, w2B+(size_t)i*262144, b2, gates, nullptr, nullptr, dtok,
                                   4096,256,256, FB_BIAS|FB_RS|FB_ATOMIC, 1048576,65536,256,0);
    residual_k<<<4096,256,0,stream>>>(zc, zcb, ftb, dtok);
  }

  // ---- decoder ----
  mfma_gemm<<<GG,256,0,stream>>>(zcb, decB, W+acum[5], nullptr, xe, nullptr, nullptr,
                                 4096,256,256, FB_BIAS|FB_WF32, 0,0,0,0);
  unpatch_k<<<4096,256,0,stream>>>(xe, d_out, flag);
}

// Round 3
// 340.202 us; speedup vs baseline: 5.2355x; 1.3756x over previous
//
#include <hip/hip_runtime.h>
#include <hip/hip_bf16.h>
#include <math.h>

// UniPhyModel: B=2,T=8,C=4,H=W=128,P=8,D=128,DEPTH=2,E=4,HD=256,Hp=Wp=16,F2=256,CPP=256
// Canonical activation layout: [n][256] where n=((b*T+t)*16+hp)*16+wp, cols = [re(128)|im(128)]
// All GEMMs: M=4096, N=256, K in {256, 2304}; weights pre-transposed to [N][K] bf16.

#define NIN 28
typedef unsigned short u16;
typedef __attribute__((ext_vector_type(8))) short bf16x8;
typedef __attribute__((ext_vector_type(4))) float f32x4;
typedef __attribute__((ext_vector_type(8))) unsigned short us8;

__device__ __forceinline__ float b2f(u16 u){ union{unsigned i;float f;}v; v.i=((unsigned)u)<<16; return v.f; }
__device__ __forceinline__ u16 f2b(float x){ __hip_bfloat16 h=__float2bfloat16(x); return *(u16*)&h; }
__device__ __forceinline__ float loadraw(const void* p, size_t i, int bf){
  return bf? b2f(((const u16*)p)[i]) : ((const float*)p)[i];
}
__device__ __forceinline__ float d_sigmoid(float x){ return 1.0f/(1.0f+expf(-x)); }
__device__ __forceinline__ float d_softplus(float x){ return fmaxf(x,0.0f)+log1pf(expf(-fabsf(x))); }
__device__ __forceinline__ float d_gelu(float x){
  const float c=0.7978845608028654f;
  return 0.5f*x*(1.0f+tanhf(c*(x+0.044715f*x*x*x)));
}

// ---------- dtype detect + convert small f32 params into arena ----------
__global__ void detect_k(const void* lnspg, int* flag){
  unsigned w=*(const unsigned*)lnspg;        // ln_sp_g is all-ones
  *flag=(w==0x3F803F80u)?1:0;                // bf16 pair of 1.0 vs f32 1.0
}

struct CvtArgs { const void* src[NIN]; int cum[NIN+1]; };

__global__ __launch_bounds__(256) void convert_k(CvtArgs a, const int* flag, float* dst, int total){
  int g=blockIdx.x*256+threadIdx.x;
  if(g>=total) return;
  int i=0;
  while(i<NIN-1 && g>=a.cum[i+1]) i++;
  int local=g-a.cum[i];
  dst[g]=loadraw(a.src[i], local, *flag);
}

// ---------- weight prep ----------
__global__ __launch_bounds__(256) void prep_enc(const void* wre, const void* wim, u16* dst, const int* flag){
  int idx=blockIdx.x*256+threadIdx.x;        // 65536
  int n=idx>>8, k=idx&255;
  int bf=*flag;
  float v=(n<128)? loadraw(wre,(size_t)k*128+n,bf) : loadraw(wim,(size_t)k*128+(n-128),bf);
  dst[idx]=f2b(v);
}

__global__ __launch_bounds__(256) void prep_conv(const void* w, u16* dst, const int* flag){
  int idx=blockIdx.x*256+threadIdx.x;        // 2*256*2304 = 1179648
  if(idx>=1179648) return;
  int i=idx/589824; int r=idx-i*589824;
  int o=r/2304; int k=r-o*2304;
  int kg=k>>8, ic=k&255; int ky=kg/3, kx=kg-3*ky;
  size_t src=((((size_t)i*256+o)*256+ic)*3+ky)*3+kx;
  dst[idx]=f2b(loadraw(w,src,*flag));
}

// cplxB[mat][n][k] for mats {E d0, E d1, Dc d0, Dc d1}: real-ified complex right-mult
__global__ __launch_bounds__(256) void prep_cplx(const void* ere, const void* eim,
    const void* dre, const void* dim, u16* dst, const int* flag){
  int idx=blockIdx.x*256+threadIdx.x;        // 4*65536
  int mat=idx>>16; int r=idx&65535; int n=r>>8, k=r&255;
  int depth=mat&1; int isD=mat>>1;
  const void* re=isD? dre:ere; const void* im=isD? dim:eim;
  size_t base=(size_t)depth*16384;
  int bf=*flag;
  float v;
  if(k<128){
    if(n<128) v= loadraw(re, base+(size_t)k*128+n, bf);
    else      v= loadraw(im, base+(size_t)k*128+(n-128), bf);
  }else{
    int kk=k-128;
    if(n<128) v=-loadraw(im, base+(size_t)kk*128+n, bf);
    else      v= loadraw(re, base+(size_t)kk*128+(n-128), bf);
  }
  dst[idx]=f2b(v);
}

__global__ __launch_bounds__(256) void transpose256(const void* src, u16* dst, int nmat, const int* flag){
  int idx=blockIdx.x*256+threadIdx.x;
  if(idx>=nmat*65536) return;
  int m=idx>>16; int r=idx&65535; int n=r>>8, k=r&255;
  dst[idx]=f2b(loadraw(src,(size_t)m*65536+(size_t)k*256+n,*flag));
}

// ---------- patch gather -> bf16 f[n][cpp] ----------
__global__ __launch_bounds__(256) void gather_k(const void* x, u16* f, const int* flag){
  int i=blockIdx.x*256+threadIdx.x;          // 1048576
  int cpp=i&255, n=i>>8;
  int wp=n&15, hp=(n>>4)&15, bt=n>>8;
  int c=cpp>>6, ph=(cpp>>3)&7, pw=cpp&7;
  size_t src=(((size_t)bt*4+c)<<14)+(size_t)((hp*8+ph)<<7)+(wp*8+pw);
  f[i]= (*flag)? ((const u16*)x)[src] : f2b(((const float*)x)[src]);
}

// ---------- unified MFMA GEMM ----------
#define FB_BIAS 1
#define FB_GELU 2
#define FB_RS 4
#define FB_ATOMIC 8
#define FB_ADDTO 16
#define FB_WF32 32
#define FB_WBF16 64
#define FB_CONV 128

__global__ __launch_bounds__(256) void mfma_gemm(
    const u16* __restrict__ A, const u16* __restrict__ Bt,
    const float* __restrict__ bias, const float* __restrict__ rowscale,
    float* __restrict__ Cf, u16* __restrict__ Cb, float* __restrict__ Cat,
    int M, int N, int K, int flags,
    long aStride, long bStride, long biasStride, long cStride)
{
  __shared__ u16 As[64][72];                  // 144B row stride: 16B-aligned, 4-bank rotate/row
  __shared__ u16 Bs[64][72];
  const int e = blockIdx.z;
  A  += (size_t)e*aStride;
  Bt += (size_t)e*bStride;
  if(bias) bias += (size_t)e*biasStride;
  const int bn = blockIdx.x*64, bm = blockIdx.y*64;
  const int tid = threadIdx.x, l = tid&63, w = tid>>6;
  const int wm = w>>1, wn = w&1;
  const us8 z8 = {0,0,0,0,0,0,0,0};
  us8 ra[2], rb[2];

  auto loadA=[&](int k0, int i){
    int c = tid + (i<<8); int row=c>>3, col8=(c&7)<<3;
    if (flags & FB_CONV){
      int m = bm + row; int bt=m>>8, rem=m&255, hp=rem>>4, wp=rem&15;
      int gk=k0+col8; int kg=gk>>8, ic=gk&255; int ky=kg/3, kx=kg-3*ky;
      int y=hp+ky-1, x=wp+kx-1;
      if ((unsigned)y<16u && (unsigned)x<16u)
        ra[i] = *(const us8*)&A[(((size_t)(bt*16+y))*16+x)*256+ic];
      else ra[i] = z8;
    } else {
      ra[i] = *(const us8*)&A[(size_t)(bm+row)*K + k0 + col8];
    }
  };
  auto loadB=[&](int k0, int i){
    int c = tid + (i<<8); int row=c>>3, col8=(c&7)<<3;
    rb[i] = *(const us8*)&Bt[(size_t)(bn+row)*K + k0 + col8];
  };

  loadA(0,0); loadA(0,1); loadB(0,0); loadB(0,1);

  f32x4 zf = {0.f,0.f,0.f,0.f};
  f32x4 acc[2][2];
  acc[0][0]=zf; acc[0][1]=zf; acc[1][0]=zf; acc[1][1]=zf;

  const int kSteps = K>>6;
  for(int ks=0; ks<kSteps; ++ks){
    __syncthreads();                          // prior reads done
    {
      int c0=tid, c1=tid+256;
      *(us8*)&As[c0>>3][(c0&7)<<3] = ra[0];
      *(us8*)&As[c1>>3][(c1&7)<<3] = ra[1];
      *(us8*)&Bs[c0>>3][(c0&7)<<3] = rb[0];
      *(us8*)&Bs[c1>>3][(c1&7)<<3] = rb[1];
    }
    if(ks+1<kSteps){ int k0=(ks+1)<<6; loadA(k0,0); loadA(k0,1); loadB(k0,0); loadB(k0,1); }
    __syncthreads();                          // tile ready; next-tile loads in flight
    #pragma unroll
    for(int kk=0; kk<64; kk+=32){
      const int kc = kk + ((l>>4)<<3);
      bf16x8 a0 = *(const bf16x8*)&As[wm*32      + (l&15)][kc];
      bf16x8 a1 = *(const bf16x8*)&As[wm*32 + 16 + (l&15)][kc];
      bf16x8 b0 = *(const bf16x8*)&Bs[wn*32      + (l&15)][kc];
      bf16x8 b1 = *(const bf16x8*)&Bs[wn*32 + 16 + (l&15)][kc];
      acc[0][0] = __builtin_amdgcn_mfma_f32_16x16x32_bf16(a0,b0,acc[0][0],0,0,0);
      acc[0][1] = __builtin_amdgcn_mfma_f32_16x16x32_bf16(a0,b1,acc[0][1],0,0,0);
      acc[1][0] = __builtin_amdgcn_mfma_f32_16x16x32_bf16(a1,b0,acc[1][0],0,0,0);
      acc[1][1] = __builtin_amdgcn_mfma_f32_16x16x32_bf16(a1,b1,acc[1][1],0,0,0);
    }
  }

  const int rr = (l>>4)<<2;                   // C/D: col=lane&15, row=(lane>>4)*4+reg (m89/m91)
  const int cc = l&15;
  #pragma unroll
  for(int mi=0;mi<2;mi++)
  #pragma unroll
  for(int ni=0;ni<2;ni++)
  #pragma unroll
  for(int r=0;r<4;r++){
    int m = bm + wm*32 + mi*16 + rr + r;
    int n = bn + wn*32 + ni*16 + cc;
    float v = acc[mi][ni][r];
    if(flags&FB_BIAS) v += bias[n];
    if(flags&FB_GELU) v = d_gelu(v);
    if(flags&FB_RS)   v *= rowscale[(size_t)m*4 + e];
    size_t o = (size_t)e*cStride + (size_t)m*N + n;
    if(flags&FB_ATOMIC){ atomicAdd(&Cat[(size_t)m*N+n], v); continue; }
    if(flags&FB_ADDTO){ v += Cf[o]; }
    if(flags&(FB_WF32|FB_ADDTO)) Cf[o]=v;
    if(flags&FB_WBF16) Cb[o]=f2b(v);
  }
}

// ---------- LayerNorm over 256 cols, f32 in -> bf16 out ----------
__global__ __launch_bounds__(256) void ln_k(const float* __restrict__ X,
    const float* __restrict__ g, const float* __restrict__ b, u16* __restrict__ out){
  int n=blockIdx.x, tid=threadIdx.x;
  float v=X[(size_t)n*256+tid];
  __shared__ float red[256];
  red[tid]=v; __syncthreads();
  for(int s=128;s>0;s>>=1){ if(tid<s) red[tid]+=red[tid+s]; __syncthreads(); }
  float mean=red[0]*(1.0f/256.0f);
  __syncthreads();
  float d=v-mean;
  red[tid]=d*d; __syncthreads();
  for(int s=128;s>0;s>>=1){ if(tid<s) red[tid]+=red[tid+s]; __syncthreads(); }
  float rs=rsqrtf(red[0]*(1.0f/256.0f)+1e-5f);
  out[(size_t)n*256+tid]=f2b(d*rs*g[tid]+b[tid]);
}

// ---------- spatial-mean partials: xm4[bt][ch][256] = sum of 64 spatial rows ----------
__global__ __launch_bounds__(256) void reduce_xm4(const float* __restrict__ xe, float* __restrict__ xm4){
  int bt=blockIdx.x, ch=blockIdx.y, c=threadIdx.x;
  const float* base = xe + ((size_t)bt*256 + ch*64)*256 + c;
  float s=0.f;
  #pragma unroll 4
  for(int sp=0;sp<64;sp++) s += base[(size_t)sp*256];
  xm4[(bt*4+ch)*256+c]=s;
}

// ---------- batched gate/src matvecs for all 16 (b,t): s2=xm@sW+sb, gt=sigmoid(xm@gW+gb) ----------
__global__ __launch_bounds__(384) void gate_src_k(const float* __restrict__ xm4,
    const float* __restrict__ sW, const float* __restrict__ sb,
    const float* __restrict__ gW, const float* __restrict__ gb,
    float* __restrict__ xm, float* __restrict__ s2, float* __restrict__ gt){
  int bt=blockIdx.x, tid=threadIdx.x;
  __shared__ float inp[256];
  if(tid<256){
    float v=(xm4[(bt*4+0)*256+tid]+xm4[(bt*4+1)*256+tid]
            +xm4[(bt*4+2)*256+tid]+xm4[(bt*4+3)*256+tid])*(1.0f/256.0f);
    inp[tid]=v; xm[bt*256+tid]=v;
  }
  __syncthreads();
  if(tid<256){
    float acc=sb[tid];
    for(int k=0;k<256;k++) acc+=inp[k]*sW[k*256+tid];
    s2[bt*256+tid]=acc;
  }else{
    int d=tid-256;
    float acc=gb[d];
    for(int k=0;k<256;k++) acc+=inp[k]*gW[k*128+d];
    gt[bt*128+d]=d_sigmoid(acc);
  }
}

// ---------- elementwise flux recurrence over T=8 (1 block, 512 threads) ----------
__global__ __launch_bounds__(512) void flux_rec_k(const float* __restrict__ xm,
    const float* __restrict__ s2, const float* __restrict__ gt,
    const float* __restrict__ fdec, float* __restrict__ fluxbuf,
    float* __restrict__ fseq, int initFlux){
  int tid=threadIdx.x;                       // b(1b) | im(1b) | d(7b)
  int d=tid&127, im=(tid>>7)&1, b=tid>>8;
  float fl = initFlux? 0.f : fluxbuf[b*256+im*128+d];
  float dec = d_sigmoid(fdec[d]);
  for(int t=0;t<8;t++){
    int bt=b*8+t;
    float g=gt[bt*128+d];
    float x=xm[bt*256+im*128+d];
    float s=s2[bt*256+im*128+d];
    fl = dec*fl + g*x + (1.0f-g)*s;
    fseq[bt*256+im*128+d]=fl;
  }
  fluxbuf[b*256+im*128+d]=fl;
}

// ---------- second gate: gbuf[bt][128] = sigmoid(fseq@gW+gb) ----------
__global__ __launch_bounds__(128) void gate2_k(const float* __restrict__ fseq,
    const float* __restrict__ gW, const float* __restrict__ gb, float* __restrict__ gbuf){
  int bt=blockIdx.x, d=threadIdx.x;
  __shared__ float inp[256];
  inp[d]=fseq[bt*256+d]; inp[128+d]=fseq[bt*256+128+d];
  __syncthreads();
  float acc=gb[d];
  for(int k=0;k<256;k++) acc+=inp[k]*gW[k*128+d];
  gbuf[bt*128+d]=d_sigmoid(acc);
}

// ---------- ZOH operators ----------
__global__ __launch_bounds__(256) void opd_opf_k(const float* __restrict__ dt,
    const float* __restrict__ lam_re, const float* __restrict__ lam_im,
    float* __restrict__ odr_, float* __restrict__ odi_, float* __restrict__ ofr_, float* __restrict__ ofi_){
  int idx=blockIdx.x*256+threadIdx.x;
  if(idx>=1024) return;
  int t=idx>>7, d=idx&127;
  float lr=-d_softplus(lam_re[d]);
  float li=lam_im[d];
  float dtv=dt[t];
  float er=expf(dtv*lr);
  float odr=er*cosf(dtv*li), odi=er*sinf(dtv*li);
  float den=lr*lr+li*li;
  float ar=odr-1.0f, ai=odi;
  odr_[idx]=odr; odi_[idx]=odi;
  ofr_[idx]=(ar*lr+ai*li)/den;
  ofi_[idx]=(ai*lr-ar*li)/den;
}

// ---------- fused forcing + inclusive time scan -> uo bf16 ----------
__global__ __launch_bounds__(256) void fscan_t(const float* __restrict__ xe,
    const float* __restrict__ gbuf, const float* __restrict__ ss,
    const float* __restrict__ odr, const float* __restrict__ odi,
    const float* __restrict__ ofr, const float* __restrict__ ofi, u16* __restrict__ uo){
  int idx=blockIdx.x*256+threadIdx.x;        // 65536 = (b,s,d)
  int d=idx&127, s=(idx>>7)&255, b=idx>>15;
  float hr=0.f, hi=0.f;
  for(int t=0;t<8;t++){
    int bt=b*8+t;
    size_t n=(size_t)bt*256+s;
    float g=gbuf[bt*128+d];
    float sr=ss[bt*256+d], si=ss[bt*256+128+d];
    float xr=xe[n*256+d], xi=xe[n*256+128+d];
    float fr=xr*g+sr*(1.0f-g), fi=xi*g+si*(1.0f-g);
    float pr=ofr[t*128+d], pi=ofi[t*128+d];
    float ur=fr*pr-fi*pi, ui=fr*pi+fi*pr;
    float ar=odr[t*128+d], ai=odi[t*128+d];
    float nr=ar*hr-ai*hi+ur, ni=ar*hi+ai*hr+ui;
    hr=nr; hi=ni;
    uo[n*256+d]=f2b(hr); uo[n*256+128+d]=f2b(hi);
  }
}

// ---------- router softmax ----------
__global__ __launch_bounds__(256) void gates_k(const u16* __restrict__ ft,
    const float* __restrict__ rtr, float* __restrict__ gates){
  int m=blockIdx.x*256+threadIdx.x;          // 4096
  float a0=0,a1=0,a2=0,a3=0;
  for(int k=0;k<256;k++){
    float v=b2f(ft[(size_t)m*256+k]);
    a0+=v*rtr[k*4+0]; a1+=v*rtr[k*4+1]; a2+=v*rtr[k*4+2]; a3+=v*rtr[k*4+3];
  }
  float mx=fmaxf(fmaxf(a0,a1),fmaxf(a2,a3));
  float e0=expf(a0-mx),e1=expf(a1-mx),e2=expf(a2-mx),e3=expf(a3-mx);
  float s=1.0f/(e0+e1+e2+e3);
  gates[m*4+0]=e0*s; gates[m*4+1]=e1*s; gates[m*4+2]=e2*s; gates[m*4+3]=e3*s;
}

// ---------- zc += ft + dtok ; refresh zc bf16 ----------
__global__ __launch_bounds__(256) void residual_k(float* __restrict__ zc, u16* __restrict__ zcb,
    const u16* __restrict__ ft, const float* __restrict__ dtok){
  size_t i=(size_t)blockIdx.x*256+threadIdx.x;  // 1048576
  float v=zc[i]+b2f(ft[i])+dtok[i];
  zc[i]=v; zcb[i]=f2b(v);
}

// ---------- unpatchify + output ----------
__global__ __launch_bounds__(256) void unpatch_k(const float* __restrict__ fo, void* dout, const int* flag){
  int o=blockIdx.x*256+threadIdx.x;          // 1048576
  int w=o&127;
  int y=(o>>7)&127;
  int c=(o>>14)&3;
  int bt=o>>16;
  int hp=y>>3, ph=y&7, wp=w>>3, pw=w&7;
  int n=(bt<<8)+(hp<<4)+wp;
  int cpp=(c<<6)+(ph<<3)+pw;
  float v=fo[(size_t)n*256+cpp];
  if(*flag) ((__hip_bfloat16*)dout)[o]=__float2bfloat16(v);
  else      ((float*)dout)[o]=v;
}

extern "C" void kernel_launch(void* const* d_in, const int* in_sizes, int n_in,
                              void* d_out, int out_size, void* d_ws, size_t ws_size,
                              hipStream_t stream){
  (void)out_size; (void)ws_size; (void)n_in;
  // arena holds f32 copies of everything EXCEPT x (index 0, biggest input)
  int acum[NIN+1]; acum[0]=0;
  for(int i=0;i<NIN;i++) acum[i+1]=acum[i]+((i==0)?0:in_sizes[i]);
  const int totalA=acum[NIN];
  float* W=(float*)d_ws;
  size_t off=((size_t)totalA+63)&~(size_t)63;
  int*   flag =(int*)(W+off); off+=64;
  float* zc   =W+off; off+=1048576;
  float* xe   =W+off; off+=1048576;          // also xo, fo (time-disjoint)
  float* dtok =W+off; off+=1048576;
  u16*  zcb  =(u16*)(W+off); off+=524288;
  u16*  xnb  =(u16*)(W+off); off+=524288;
  u16*  uob  =(u16*)(W+off); off+=524288;    // also encoder input f_b
  u16*  ftb  =(u16*)(W+off); off+=524288;
  u16*  hmid =(u16*)(W+off); off+=2097152;   // [4][4096][256]
  u16*  encB =(u16*)(W+off); off+=32768;
  u16*  decB =(u16*)(W+off); off+=32768;
  u16*  convB=(u16*)(W+off); off+=589824;    // [2][256][2304]
  u16*  cplxB=(u16*)(W+off); off+=131072;    // [4][256][256]: E0,E1,D0,D1
  u16*  w1B  =(u16*)(W+off); off+=262144;    // [8][256][256]
  u16*  w2B  =(u16*)(W+off); off+=262144;
  float* xm4  =W+off; off+=16384;
  float* xm   =W+off; off+=4096;
  float* s2   =W+off; off+=4096;
  float* fseq =W+off; off+=4096;
  float* gt   =W+off; off+=2048;
  float* gbuf =W+off; off+=2048;
  float* odr  =W+off; off+=1024;
  float* odi  =W+off; off+=1024;
  float* ofr  =W+off; off+=1024;
  float* ofi  =W+off; off+=1024;
  float* gates=W+off; off+=16384;
  float* fluxb=W+off; off+=512;

  // ---- detect + convert + weight prep ----
  detect_k<<<1,1,0,stream>>>(d_in[6], flag);
  CvtArgs ca;
  for(int i=0;i<NIN;i++) ca.src[i]=d_in[i];
  for(int i=0;i<=NIN;i++) ca.cum[i]=acum[i];
  convert_k<<<(totalA+255)/256,256,0,stream>>>(ca, flag, W, totalA);
  prep_enc<<<256,256,0,stream>>>(d_in[2], d_in[3], encB, flag);
  transpose256<<<256,256,0,stream>>>(d_in[4], decB, 1, flag);
  prep_conv<<<4608,256,0,stream>>>(d_in[8], convB, flag);
  prep_cplx<<<1024,256,0,stream>>>(d_in[10], d_in[11], d_in[12], d_in[13], cplxB, flag);
  transpose256<<<2048,256,0,stream>>>(d_in[24], w1B, 8, flag);
  transpose256<<<2048,256,0,stream>>>(d_in[26], w2B, 8, flag);

  const dim3 GG(4,64,1);
  // ---- encoder: zc = f @ [Wre|Wim] ----
  gather_k<<<4096,256,0,stream>>>(d_in[0], uob, flag);
  mfma_gemm<<<GG,256,0,stream>>>(uob, encB, nullptr, nullptr, zc, zcb, nullptr,
                                 4096,256,256, FB_WF32|FB_WBF16, 0,0,0,0);

  for(int i=0;i<2;i++){
    const float* lnspg=W+acum[6]+i*256;
    const float* lnspb=W+acum[7]+i*256;
    const float* convb=W+acum[9]+i*256;
    const float* gW   =W+acum[14]+i*32768;
    const float* gb   =W+acum[15]+i*128;
    const float* sW   =W+acum[16]+i*65536;
    const float* sb   =W+acum[17]+i*256;
    const float* fdec =W+acum[18]+i*128;
    const float* lamre=W+acum[19]+i*128;
    const float* lamim=W+acum[20]+i*128;
    const float* lntg =W+acum[21]+i*256;
    const float* lntb =W+acum[22]+i*256;
    const float* rtr  =W+acum[23]+i*1024;
    const float* b1   =W+acum[25]+i*1024;
    const float* b2   =W+acum[27]+i*1024;

    // spatial branch: LN -> implicit-GEMM conv (+bias) accumulated into zc
    ln_k<<<4096,256,0,stream>>>(zc, lnspg, lnspb, xnb);
    mfma_gemm<<<GG,256,0,stream>>>(xnb, convB+(size_t)i*589824, convb, nullptr, zc, zcb, nullptr,
                                   4096,256,2304, FB_CONV|FB_BIAS|FB_ADDTO|FB_WBF16, 0,0,0,0);
    // eigen encode (complex as real 256x256)
    mfma_gemm<<<GG,256,0,stream>>>(zcb, cplxB+(size_t)i*65536, nullptr, nullptr, xe, nullptr, nullptr,
                                   4096,256,256, FB_WF32, 0,0,0,0);
    // flux path: partial means -> batched gate/src -> tiny recurrence -> second gate
    reduce_xm4<<<dim3(16,4),256,0,stream>>>(xe, xm4);
    gate_src_k<<<16,384,0,stream>>>(xm4, sW, sb, gW, gb, xm, s2, gt);
    flux_rec_k<<<1,512,0,stream>>>(xm, s2, gt, fdec, fluxb, fseq, (i==0)?1:0);
    gate2_k<<<16,128,0,stream>>>(fseq, gW, gb, gbuf);
    opd_opf_k<<<4,256,0,stream>>>(W+acum[1], lamre, lamim, odr, odi, ofr, ofi);
    fscan_t<<<256,256,0,stream>>>(xe, gbuf, s2, odr, odi, ofr, ofi, uob);
    // basis decode + LN
    mfma_gemm<<<GG,256,0,stream>>>(uob, cplxB+(size_t)(2+i)*65536, nullptr, nullptr, xe, nullptr, nullptr,
                                   4096,256,256, FB_WF32, 0,0,0,0);
    ln_k<<<4096,256,0,stream>>>(xe, lntg, lntb, ftb);
    // MoE
    gates_k<<<16,256,0,stream>>>(ftb, rtr, gates);
    hipMemsetAsync(dtok, 0, 1048576*sizeof(float), stream);
    mfma_gemm<<<dim3(4,64,4),256,0,stream>>>(ftb, w1B+(size_t)i*262144, b1, nullptr, nullptr, hmid, nullptr,
                                   4096,256,256, FB_BIAS|FB_GELU|FB_WBF16, 0,65536,256,1048576);
    mfma_gemm<<<dim3(4,64,4),256,0,stream>>>(hmid, w2B+(size_t)i*262144, b2, gates, nullptr, nullptr, dtok,
                                   4096,256,256, FB_BIAS|FB_RS|FB_ATOMIC, 1048576,65536,256,0);
    residual_k<<<4096,256,0,stream>>>(zc, zcb, ftb, dtok);
  }

  // ---- decoder ----
  mfma_gemm<<<GG,256,0,stream>>>(zcb, decB, W+acum[5], nullptr, xe, nullptr, nullptr,
                                 4096,256,256, FB_BIAS|FB_WF32, 0,0,0,0);
  unpatch_k<<<4096,256,0,stream>>>(xe, d_out, flag);
}

// Round 4
// 211.931 us; speedup vs baseline: 8.4043x; 1.6053x over previous
//
#include <hip/hip_runtime.h>
#include <hip/hip_bf16.h>
#include <math.h>

// UniPhyModel: B=2,T=8,C=4,H=W=128,P=8,D=128,DEPTH=2,E=4,HD=256,Hp=Wp=16,F2=256,CPP=256
// Activation layout: [n][256], n=((b*T+t)*16+hp)*16+wp, cols=[re(128)|im(128)]

#define NIN 28
typedef unsigned short u16;
typedef __attribute__((ext_vector_type(8))) short bf16x8;
typedef __attribute__((ext_vector_type(4))) float f32x4;
typedef __attribute__((ext_vector_type(8))) unsigned short us8;
typedef __attribute__((ext_vector_type(4))) unsigned short us4;

__device__ __forceinline__ float b2f(u16 u){ union{unsigned i;float f;}v; v.i=((unsigned)u)<<16; return v.f; }
__device__ __forceinline__ u16 f2b(float x){ __hip_bfloat16 h=__float2bfloat16(x); return *(u16*)&h; }
__device__ __forceinline__ float loadraw(const void* p, size_t i, int bf){
  return bf? b2f(((const u16*)p)[i]) : ((const float*)p)[i];
}
__device__ __forceinline__ float d_sigmoid(float x){ return 1.0f/(1.0f+expf(-x)); }
__device__ __forceinline__ float d_softplus(float x){ return fmaxf(x,0.0f)+log1pf(expf(-fabsf(x))); }
__device__ __forceinline__ float d_gelu(float x){
  const float c=0.7978845608028654f;
  return 0.5f*x*(1.0f+tanhf(c*(x+0.044715f*x*x*x)));
}

// ---------- dtype detect ----------
__global__ void detect_k(const void* lnspg, int* flag){
  unsigned w=*(const unsigned*)lnspg;
  *flag=(w==0x3F803F80u)?1:0;
}

// ---------- mega prep: f32 converts + all bf16 weight prep in ONE kernel ----------
#define NF32 17
struct MP {
  const void* src[NIN];
  int f32dst[NF32]; int f32cum[NF32+1];
  int seg[7];   // cumulative ends: S0 f32, S1 enc, S2 dec, S3 conv, S4 cplx, S5 w1, S6 w2
};

__global__ __launch_bounds__(256) void mega_prep(MP a, const int* __restrict__ flag, float* __restrict__ W,
    u16* __restrict__ encB, u16* __restrict__ decB, u16* __restrict__ convB,
    u16* __restrict__ cplxB, u16* __restrict__ w1B, u16* __restrict__ w2c,
    const int* f32srcIdx_unused){
  int g=blockIdx.x*256+threadIdx.x;
  if(g>=a.seg[6]) return;
  int bf=*flag;
  if(g<a.seg[0]){
    // f32 convert of small params
    int i=0;
    while(i<NF32-1 && g>=a.f32cum[i+1]) i++;
    int local=g-a.f32cum[i];
    // map i -> input index
    const int needs[NF32]={1,5,6,7,9,14,15,16,17,18,19,20,21,22,23,25,27};
    W[a.f32dst[i]+local]=loadraw(a.src[needs[i]], local, bf);
  } else if(g<a.seg[1]){            // encB[n][k]
    int idx=g-a.seg[0]; int n=idx>>8, k=idx&255;
    float v=(n<128)? loadraw(a.src[2],(size_t)k*128+n,bf) : loadraw(a.src[3],(size_t)k*128+(n-128),bf);
    encB[idx]=f2b(v);
  } else if(g<a.seg[2]){            // decB[n][k]=dec_W[k][n]
    int idx=g-a.seg[1]; int n=idx>>8, k=idx&255;
    decB[idx]=f2b(loadraw(a.src[4],(size_t)k*256+n,bf));
  } else if(g<a.seg[3]){            // convB[i][o][k], k=(ky*3+kx)*256+ic
    int idx=g-a.seg[2];
    int i=idx/589824; int r=idx-i*589824;
    int o=r/2304; int k=r-o*2304;
    int kg=k>>8, ic=k&255; int ky=kg/3, kx=kg-3*ky;
    size_t s=((((size_t)i*256+o)*256+ic)*3+ky)*3+kx;
    convB[idx]=f2b(loadraw(a.src[8],s,bf));
  } else if(g<a.seg[4]){            // cplxB[mat][n][k]: E0,E1,D0,D1 real-ified
    int idx=g-a.seg[3];
    int mat=idx>>16; int r=idx&65535; int n=r>>8, k=r&255;
    int depth=mat&1; int isD=mat>>1;
    const void* re=isD? a.src[12]:a.src[10];
    const void* im=isD? a.src[13]:a.src[11];
    size_t base=(size_t)depth*16384;
    float v;
    if(k<128){ v = (n<128)? loadraw(re,base+(size_t)k*128+n,bf) : loadraw(im,base+(size_t)k*128+(n-128),bf); }
    else{ int kk=k-128;
      v = (n<128)? -loadraw(im,base+(size_t)kk*128+n,bf) : loadraw(re,base+(size_t)kk*128+(n-128),bf); }
    cplxB[idx]=f2b(v);
  } else if(g<a.seg[5]){            // w1B[(i*4+e)][n][k]=W1[(i,e)][k][n]
    int idx=g-a.seg[4]; int m=idx>>16; int r=idx&65535; int n=r>>8, k=r&255;
    w1B[idx]=f2b(loadraw(a.src[24],(size_t)m*65536+(size_t)k*256+n,bf));
  } else {                          // w2c[i][n][e*256+h]=W2[(i,e)][h][n]
    int idx=g-a.seg[5];
    int i=idx>>18; int r=idx&262143; int n=r>>10; int k=r&1023;
    int e=k>>8, h=k&255;
    size_t s=(((size_t)(i*4+e)*256+h)*256+n);
    w2c[idx]=f2b(loadraw(a.src[26],s,bf));
  }
}

// ---------- unified MFMA GEMM, templated flags ----------
#define FB_BIAS 1
#define FB_GELU 2
#define FB_RS 4
#define FB_ADDTO 8
#define FB_WF32 16
#define FB_WBF16 32
#define FB_CONV 64
#define FB_GATHER 128
#define FB_MOE2 256
#define FB_UNPATCH 512

template<int FLAGS>
__global__ __launch_bounds__(512,2) void mfma_gemm(
    const void* __restrict__ Asrc, const u16* __restrict__ Bt,
    const float* __restrict__ bias, const float* __restrict__ gates,
    float* __restrict__ Cf, u16* __restrict__ Cb,
    const u16* __restrict__ Xtra, void* __restrict__ Cout, const int* __restrict__ flagp,
    int K, long aE, long bE, long biasE, long cE, long cRow)
{
  __shared__ u16 As[64][72];                 // 144B rows: 4-bank rotation -> <=2-way on b128 reads
  __shared__ u16 Bs[64][72];
  const int e=blockIdx.z;
  const u16* A=(const u16*)Asrc + (size_t)e*aE;
  Bt += (size_t)e*bE;
  const float* biasp = bias? bias+(size_t)e*biasE : nullptr;
  const int bn=blockIdx.x*64, bm=blockIdx.y*64;
  const int tid=threadIdx.x, l=tid&63, w=tid>>6;
  const int wm=w&3, wn=w>>2;
  const int row=tid>>3, col8=(tid&7)<<3;
  int bf=0;
  if(FLAGS&(FB_GATHER|FB_UNPATCH)) bf=*flagp;
  const us8 z8={0,0,0,0,0,0,0,0};
  us8 ra, rbv;

  auto loadA=[&](int k0){
    int gk=k0+col8;
    if(FLAGS&FB_CONV){
      int m=bm+row; int bt=m>>8, rem=m&255, hp=rem>>4, wp=rem&15;
      int kg=gk>>8, ic=gk&255; int ky=kg/3, kx=kg-3*ky;
      int y=hp+ky-1, x=wp+kx-1;
      ra = ((unsigned)y<16u && (unsigned)x<16u)?
           *(const us8*)&A[(((size_t)(bt*16+y))*16+x)*256+ic] : z8;
    } else if(FLAGS&FB_GATHER){
      int m=bm+row; int bt=m>>8, rem=m&255, hp=rem>>4, wp=rem&15;
      int c=gk>>6, ph=(gk>>3)&7;
      size_t sidx=(((size_t)bt*4+c)<<14)+(size_t)((hp*8+ph)<<7)+wp*8;
      if(bf) ra=*(const us8*)&((const u16*)Asrc)[sidx];
      else{
        const float* xf=(const float*)Asrc + sidx;
        us8 t;
        #pragma unroll
        for(int j=0;j<8;j++) t[j]=f2b(xf[j]);
        ra=t;
      }
    } else {
      ra=*(const us8*)&A[(size_t)(bm+row)*K+gk];
    }
  };
  auto loadB=[&](int k0){ rbv=*(const us8*)&Bt[(size_t)(bn+row)*K+k0+col8]; };

  loadA(0); loadB(0);
  f32x4 acc0={0.f,0.f,0.f,0.f}, acc1={0.f,0.f,0.f,0.f};
  const int kSteps=K>>6;
  for(int ks=0; ks<kSteps; ++ks){
    __syncthreads();
    *(us8*)&As[row][col8]=ra;
    *(us8*)&Bs[row][col8]=rbv;
    if(ks+1<kSteps){ loadA((ks+1)<<6); loadB((ks+1)<<6); }
    __syncthreads();
    #pragma unroll
    for(int kk=0;kk<64;kk+=32){
      const int kc=kk+((l>>4)<<3);
      bf16x8 a =*(const bf16x8*)&As[wm*16      +(l&15)][kc];
      bf16x8 b0=*(const bf16x8*)&Bs[wn*32      +(l&15)][kc];
      bf16x8 b1=*(const bf16x8*)&Bs[wn*32 + 16 +(l&15)][kc];
      acc0=__builtin_amdgcn_mfma_f32_16x16x32_bf16(a,b0,acc0,0,0,0);
      acc1=__builtin_amdgcn_mfma_f32_16x16x32_bf16(a,b1,acc1,0,0,0);
    }
  }

  const int rr=(l>>4)<<2, cc=l&15;           // C/D: col=lane&15, row=(lane>>4)*4+reg
  #pragma unroll
  for(int ni=0;ni<2;ni++){
    f32x4 av = ni? acc1:acc0;
    #pragma unroll
    for(int r=0;r<4;r++){
      int m=bm+wm*16+rr+r;
      int n=bn+wn*32+ni*16+cc;
      float v=av[r];
      if(FLAGS&FB_BIAS) v+=biasp[n];
      if(FLAGS&FB_GELU) v=d_gelu(v);
      if(FLAGS&FB_RS)   v*=gates[(size_t)m*4+e];
      if(FLAGS&FB_MOE2){
        #pragma unroll
        for(int ee=0;ee<4;ee++) v+=gates[(size_t)m*4+ee]*bias[ee*256+n];
        v+=b2f(Xtra[(size_t)m*256+n]);
      }
      if(FLAGS&FB_UNPATCH){
        int bt=m>>8, hp=(m>>4)&15, wp=m&15;
        int c=n>>6, ph=(n>>3)&7, pw=n&7;
        size_t o=((size_t)bt<<16)|((size_t)c<<14)|((size_t)(hp*8+ph)<<7)|(size_t)(wp*8+pw);
        if(bf) ((__hip_bfloat16*)Cout)[o]=__float2bfloat16(v);
        else   ((float*)Cout)[o]=v;
        continue;
      }
      size_t o=(size_t)e*cE + (size_t)m*cRow + n;
      if(FLAGS&FB_ADDTO) v+=Cf[o];
      if(FLAGS&(FB_WF32|FB_ADDTO)) Cf[o]=v;
      if(FLAGS&FB_WBF16) Cb[o]=f2b(v);
    }
  }
}

// ---------- LayerNorm (wave per row) + optional fused router softmax ----------
__global__ __launch_bounds__(256) void ln4_k(const float* __restrict__ X,
    const float* __restrict__ g, const float* __restrict__ b, u16* __restrict__ out,
    const float* __restrict__ rtr, float* __restrict__ gates){
  int row=blockIdx.x*4+(threadIdx.x>>6);
  int l=threadIdx.x&63;
  f32x4 v=*(const f32x4*)&X[(size_t)row*256+l*4];
  float s=v[0]+v[1]+v[2]+v[3];
  #pragma unroll
  for(int o=32;o;o>>=1) s+=__shfl_xor(s,o);
  float mean=s*(1.0f/256.0f);
  float d0=v[0]-mean,d1=v[1]-mean,d2=v[2]-mean,d3=v[3]-mean;
  float q=d0*d0+d1*d1+d2*d2+d3*d3;
  #pragma unroll
  for(int o=32;o;o>>=1) q+=__shfl_xor(q,o);
  float rs=rsqrtf(q*(1.0f/256.0f)+1e-5f);
  float nv[4]={d0,d1,d2,d3};
  us4 o4;
  #pragma unroll
  for(int j=0;j<4;j++){ nv[j]=nv[j]*rs*g[l*4+j]+b[l*4+j]; o4[j]=f2b(nv[j]); }
  *(us4*)&out[(size_t)row*256+l*4]=o4;
  if(rtr){
    float p[4]={0.f,0.f,0.f,0.f};
    #pragma unroll
    for(int j=0;j<4;j++)
      #pragma unroll
      for(int ee=0;ee<4;ee++) p[ee]+=nv[j]*rtr[(l*4+j)*4+ee];
    #pragma unroll
    for(int ee=0;ee<4;ee++)
      #pragma unroll
      for(int o=32;o;o>>=1) p[ee]+=__shfl_xor(p[ee],o);
    if(l==0){
      float mx=fmaxf(fmaxf(p[0],p[1]),fmaxf(p[2],p[3]));
      float e0=expf(p[0]-mx),e1=expf(p[1]-mx),e2=expf(p[2]-mx),e3=expf(p[3]-mx);
      float inv=1.0f/(e0+e1+e2+e3);
      gates[row*4+0]=e0*inv; gates[row*4+1]=e1*inv; gates[row*4+2]=e2*inv; gates[row*4+3]=e3*inv;
    }
  }
}

// ---------- spatial-mean partials ----------
__global__ __launch_bounds__(256) void reduce_xm4(const float* __restrict__ xe, float* __restrict__ xm4){
  int bt=blockIdx.x, ch=blockIdx.y, c=threadIdx.x;
  const float* base=xe+((size_t)bt*256+ch*64)*256+c;
  float s=0.f;
  #pragma unroll 4
  for(int sp=0;sp<64;sp++) s+=base[(size_t)sp*256];
  xm4[(bt*4+ch)*256+c]=s;
}

// ---------- batched gate/src matvecs (blocks 0..15) + ZOH operators (block 16) ----------
__global__ __launch_bounds__(384) void gate_src_k(const float* __restrict__ xm4,
    const float* __restrict__ sW, const float* __restrict__ sb,
    const float* __restrict__ gW, const float* __restrict__ gb,
    float* __restrict__ xm, float* __restrict__ s2, float* __restrict__ gt,
    const float* __restrict__ dt, const float* __restrict__ lam_re, const float* __restrict__ lam_im,
    float* __restrict__ odr_, float* __restrict__ odi_, float* __restrict__ ofr_, float* __restrict__ ofi_){
  int tid=threadIdx.x;
  if(blockIdx.x==16){
    for(int idx=tid; idx<1024; idx+=384){
      int t=idx>>7, d=idx&127;
      float lr=-d_softplus(lam_re[d]);
      float li=lam_im[d];
      float dtv=dt[t];
      float er=expf(dtv*lr);
      float odr=er*cosf(dtv*li), odi=er*sinf(dtv*li);
      float den=lr*lr+li*li;
      float ar=odr-1.0f, ai=odi;
      odr_[idx]=odr; odi_[idx]=odi;
      ofr_[idx]=(ar*lr+ai*li)/den;
      ofi_[idx]=(ai*lr-ar*li)/den;
    }
    return;
  }
  int bt=blockIdx.x;
  __shared__ float inp[256];
  if(tid<256){
    float v=(xm4[(bt*4+0)*256+tid]+xm4[(bt*4+1)*256+tid]
            +xm4[(bt*4+2)*256+tid]+xm4[(bt*4+3)*256+tid])*(1.0f/256.0f);
    inp[tid]=v; xm[bt*256+tid]=v;
  }
  __syncthreads();
  if(tid<256){
    float acc=sb[tid];
    for(int k=0;k<256;k++) acc+=inp[k]*sW[k*256+tid];
    s2[bt*256+tid]=acc;
  }else{
    int d=tid-256;
    float acc=gb[d];
    for(int k=0;k<256;k++) acc+=inp[k]*gW[k*128+d];
    gt[bt*128+d]=d_sigmoid(acc);
  }
}

// ---------- flux recurrence (redundant per-block rescan) + second gate ----------
__global__ __launch_bounds__(128) void flux_gate2(const float* __restrict__ xm,
    const float* __restrict__ s2, const float* __restrict__ gt,
    const float* __restrict__ fdec, const float* __restrict__ fbin, float* __restrict__ fbout,
    const float* __restrict__ gW, const float* __restrict__ gb, float* __restrict__ gbuf, int init){
  int bt=blockIdx.x; int b=bt>>3, t=bt&7; int d=threadIdx.x;
  float flr = init? 0.f : fbin[b*256+d];
  float fli = init? 0.f : fbin[b*256+128+d];
  float dec = d_sigmoid(fdec[d]);
  for(int tp=0; tp<=t; tp++){
    int q=b*8+tp;
    float gv=gt[q*128+d];
    flr = dec*flr + gv*xm[q*256+d]     + (1.0f-gv)*s2[q*256+d];
    fli = dec*fli + gv*xm[q*256+128+d] + (1.0f-gv)*s2[q*256+128+d];
  }
  __shared__ float inp[256];
  inp[d]=flr; inp[128+d]=fli;
  __syncthreads();
  float acc=gb[d];
  for(int k=0;k<256;k++) acc+=inp[k]*gW[k*128+d];
  gbuf[bt*128+d]=d_sigmoid(acc);
  if(t==7){ fbout[b*256+d]=flr; fbout[b*256+128+d]=fli; }
}

// ---------- fused forcing + inclusive time scan -> uo bf16 ----------
__global__ __launch_bounds__(256) void fscan_t(const float* __restrict__ xe,
    const float* __restrict__ gbuf, const float* __restrict__ ss,
    const float* __restrict__ odr, const float* __restrict__ odi,
    const float* __restrict__ ofr, const float* __restrict__ ofi, u16* __restrict__ uo){
  int idx=blockIdx.x*256+threadIdx.x;        // (b,s,d)
  int d=idx&127, s=(idx>>7)&255, b=idx>>15;
  float hr=0.f, hi=0.f;
  for(int t=0;t<8;t++){
    int bt=b*8+t;
    size_t n=(size_t)bt*256+s;
    float g=gbuf[bt*128+d];
    float sr=ss[bt*256+d], si=ss[bt*256+128+d];
    float xr=xe[n*256+d], xi=xe[n*256+128+d];
    float fr=xr*g+sr*(1.0f-g), fi=xi*g+si*(1.0f-g);
    float pr=ofr[t*128+d], pi=ofi[t*128+d];
    float ur=fr*pr-fi*pi, ui=fr*pi+fi*pr;
    float ar=odr[t*128+d], ai=odi[t*128+d];
    float nr=ar*hr-ai*hi+ur, ni=ar*hi+ai*hr+ui;
    hr=nr; hi=ni;
    uo[n*256+d]=f2b(hr); uo[n*256+128+d]=f2b(hi);
  }
}

extern "C" void kernel_launch(void* const* d_in, const int* in_sizes, int n_in,
                              void* d_out, int out_size, void* d_ws, size_t ws_size,
                              hipStream_t stream){
  (void)out_size; (void)ws_size; (void)n_in;
  int acum[NIN+1]; acum[0]=0;
  for(int i=0;i<NIN;i++) acum[i+1]=acum[i]+((i==0)?0:in_sizes[i]);
  const int totalA=acum[NIN];
  float* W=(float*)d_ws;
  size_t off=((size_t)totalA+63)&~(size_t)63;
  int*   flag=(int*)(W+off); off+=64;
  float* zc  =W+off; off+=1048576;
  float* xe  =W+off; off+=1048576;
  u16* zcb =(u16*)(W+off); off+=524288;
  u16* xnb =(u16*)(W+off); off+=524288;
  u16* uob =(u16*)(W+off); off+=524288;
  u16* ftb =(u16*)(W+off); off+=524288;
  u16* hmid=(u16*)(W+off); off+=2097152;     // [4096][1024] u16
  u16* encB=(u16*)(W+off); off+=32768;
  u16* decB=(u16*)(W+off); off+=32768;
  u16* convB=(u16*)(W+off); off+=589824;     // [2][256][2304]
  u16* cplxB=(u16*)(W+off); off+=131072;     // [4][256][256]
  u16* w1B =(u16*)(W+off); off+=262144;      // [8][256][256]
  u16* w2c =(u16*)(W+off); off+=262144;      // [2][256][1024]
  float* xm4 =W+off; off+=16384;
  float* xm  =W+off; off+=4096;
  float* s2  =W+off; off+=4096;
  float* gt  =W+off; off+=2048;
  float* gbuf=W+off; off+=2048;
  float* odr =W+off; off+=1024;
  float* odi =W+off; off+=1024;
  float* ofr =W+off; off+=1024;
  float* ofi =W+off; off+=1024;
  float* gates=W+off; off+=16384;
  float* fbA =W+off; off+=512;
  float* fbB =W+off; off+=512;

  detect_k<<<1,1,0,stream>>>(d_in[6], flag);

  // mega-prep
  MP mp;
  for(int i=0;i<NIN;i++) mp.src[i]=d_in[i];
  const int needs[NF32]={1,5,6,7,9,14,15,16,17,18,19,20,21,22,23,25,27};
  mp.f32cum[0]=0;
  for(int j=0;j<NF32;j++){ mp.f32cum[j+1]=mp.f32cum[j]+in_sizes[needs[j]]; mp.f32dst[j]=acum[needs[j]]; }
  int s0=mp.f32cum[NF32];
  mp.seg[0]=s0;
  mp.seg[1]=mp.seg[0]+65536;
  mp.seg[2]=mp.seg[1]+65536;
  mp.seg[3]=mp.seg[2]+1179648;
  mp.seg[4]=mp.seg[3]+262144;
  mp.seg[5]=mp.seg[4]+524288;
  mp.seg[6]=mp.seg[5]+524288;
  mega_prep<<<(mp.seg[6]+255)/256,256,0,stream>>>(mp, flag, W, encB, decB, convB, cplxB, w1B, w2c, nullptr);

  const dim3 GG(4,64,1);
  // encoder: zc = patchgather(x) @ [Wre|Wim]
  mfma_gemm<FB_GATHER|FB_WF32><<<GG,512,0,stream>>>(d_in[0], encB, nullptr, nullptr,
      zc, nullptr, nullptr, nullptr, flag, 256, 0,0,0,0,256);

  for(int i=0;i<2;i++){
    const float* lnspg=W+acum[6]+i*256;
    const float* lnspb=W+acum[7]+i*256;
    const float* convb=W+acum[9]+i*256;
    const float* gWp  =W+acum[14]+i*32768;
    const float* gbp  =W+acum[15]+i*128;
    const float* sWp  =W+acum[16]+i*65536;
    const float* sbp  =W+acum[17]+i*256;
    const float* fdec =W+acum[18]+i*128;
    const float* lamre=W+acum[19]+i*128;
    const float* lamim=W+acum[20]+i*128;
    const float* lntg =W+acum[21]+i*256;
    const float* lntb =W+acum[22]+i*256;
    const float* rtr  =W+acum[23]+i*1024;
    const float* b1   =W+acum[25]+i*1024;
    const float* b2   =W+acum[27]+i*1024;

    ln4_k<<<1024,256,0,stream>>>(zc, lnspg, lnspb, xnb, nullptr, nullptr);
    mfma_gemm<FB_CONV|FB_BIAS|FB_ADDTO|FB_WBF16><<<GG,512,0,stream>>>(xnb, convB+(size_t)i*589824,
        convb, nullptr, zc, zcb, nullptr, nullptr, nullptr, 2304, 0,0,0,0,256);
    mfma_gemm<FB_WF32><<<GG,512,0,stream>>>(zcb, cplxB+(size_t)i*65536, nullptr, nullptr,
        xe, nullptr, nullptr, nullptr, nullptr, 256, 0,0,0,0,256);
    reduce_xm4<<<dim3(16,4),256,0,stream>>>(xe, xm4);
    gate_src_k<<<17,384,0,stream>>>(xm4, sWp, sbp, gWp, gbp, xm, s2, gt,
        W+acum[1], lamre, lamim, odr, odi, ofr, ofi);
    flux_gate2<<<16,128,0,stream>>>(xm, s2, gt, fdec, (i==0)?nullptr:fbA, (i==0)?fbA:fbB,
        gWp, gbp, gbuf, (i==0)?1:0);
    fscan_t<<<256,256,0,stream>>>(xe, gbuf, s2, odr, odi, ofr, ofi, uob);
    mfma_gemm<FB_WF32><<<GG,512,0,stream>>>(uob, cplxB+(size_t)(2+i)*65536, nullptr, nullptr,
        xe, nullptr, nullptr, nullptr, nullptr, 256, 0,0,0,0,256);
    ln4_k<<<1024,256,0,stream>>>(xe, lntg, lntb, ftb, rtr, gates);
    // MoE: hmid' = gates_e * gelu(ft@W1_e + b1_e)  -> [m][e*256+h] bf16
    mfma_gemm<FB_BIAS|FB_GELU|FB_RS|FB_WBF16><<<dim3(4,64,4),512,0,stream>>>(ftb, w1B+(size_t)i*262144,
        b1, gates, nullptr, hmid, nullptr, nullptr, nullptr, 256, 0,65536,256,256,1024);
    // dtok + residual + zc/zcb update, one K=1024 GEMM
    mfma_gemm<FB_MOE2|FB_ADDTO|FB_WBF16><<<GG,512,0,stream>>>(hmid, w2c+(size_t)i*262144,
        b2, gates, zc, zcb, ftb, nullptr, nullptr, 1024, 0,0,0,0,256);
  }

  // decoder + unpatchify fused
  mfma_gemm<FB_BIAS|FB_UNPATCH><<<GG,512,0,stream>>>(zcb, decB, W+acum[5], nullptr,
      nullptr, nullptr, nullptr, d_out, flag, 256, 0,0,0,0,256);
}